// Round 1
// baseline (646.926 us; speedup 1.0000x reference)
//
#include <hip/hip_runtime.h>
#include <math.h>

#define B_  2
#define S_  1024
#define H_  2048
#define F_  512          // H/4
#define KD_ 32
#define NC_ 16
#define M_  2048         // B*S tokens
#define NPROJ 184        // 4+12+40+128 packed u-rows
#define LDP 192          // proj row stride

typedef __attribute__((ext_vector_type(8))) short bf16x8;
typedef __attribute__((ext_vector_type(4))) float f32x4;

typedef __attribute__((address_space(1))) const void gvoid_t;
typedef __attribute__((address_space(3))) void lvoid_t;

// async global -> LDS, 16B per lane. LDS dest must be wave-uniform base + lane*16.
__device__ __forceinline__ void gld16(const void* g, void* l) {
    __builtin_amdgcn_global_load_lds((gvoid_t*)g, (lvoid_t*)l, 16, 0, 0);
}

__device__ __forceinline__ ushort f2bf(float f) {
    unsigned u = __float_as_uint(f);
    u += 0x7FFFu + ((u >> 16) & 1u);   // RNE
    return (ushort)(u >> 16);
}
__device__ __forceinline__ float bf2f(ushort h) {
    return __uint_as_float(((unsigned)h) << 16);
}
__device__ __forceinline__ uint4 pack_hi8(float4 a, float4 b) {
    uint4 r;
    r.x = (unsigned)f2bf(a.x) | ((unsigned)f2bf(a.y) << 16);
    r.y = (unsigned)f2bf(a.z) | ((unsigned)f2bf(a.w) << 16);
    r.z = (unsigned)f2bf(b.x) | ((unsigned)f2bf(b.y) << 16);
    r.w = (unsigned)f2bf(b.z) | ((unsigned)f2bf(b.w) << 16);
    return r;
}
__device__ __forceinline__ void pack_hilo8(float4 a, float4 b, uint4* hi, uint4* lo) {
    float v[8] = {a.x, a.y, a.z, a.w, b.x, b.y, b.z, b.w};
    unsigned h[8], l[8];
#pragma unroll
    for (int i = 0; i < 8; ++i) {
        ushort hh = f2bf(v[i]);
        h[i] = hh;
        l[i] = f2bf(v[i] - bf2f(hh));
    }
    *hi = make_uint4(h[0] | (h[1] << 16), h[2] | (h[3] << 16),
                     h[4] | (h[5] << 16), h[6] | (h[7] << 16));
    *lo = make_uint4(l[0] | (l[1] << 16), l[2] | (l[3] << 16),
                     l[4] | (l[5] << 16), l[6] | (l[7] << 16));
}

// ---------------------------------------------------------------------------
// conv_kernel: bf16 conversions + pool partials, one pass.
// blocks 0..127    : x rows blk*16..+16 -> xhi,xlo + column-sum partial[blk]
// blocks 128..1151 : lw (flat, hi only)
// blocks 1152..1407: sw1 (flat, hi+lo)
// blocks 1408..1499: u4|u12|u40|u128 -> packed ubh rows {0,4,16,56}
// ---------------------------------------------------------------------------
__global__ __launch_bounds__(256) void conv_kernel(
    const float* __restrict__ x, const float* __restrict__ lw,
    const float* __restrict__ sw1,
    const float* __restrict__ u4, const float* __restrict__ u12,
    const float* __restrict__ u40, const float* __restrict__ u128,
    ushort* __restrict__ xhi, ushort* __restrict__ xlo,
    ushort* __restrict__ lwh, ushort* __restrict__ swh,
    ushort* __restrict__ swl, ushort* __restrict__ ubh,
    float* __restrict__ partial) {
    int blk = blockIdx.x, tid = threadIdx.x;
    if (blk < 128) {
        int c0 = tid << 3;
        float cs0 = 0.f, cs1 = 0.f, cs2 = 0.f, cs3 = 0.f;
        float cs4 = 0.f, cs5 = 0.f, cs6 = 0.f, cs7 = 0.f;
        for (int r = 0; r < 16; ++r) {
            size_t off = (size_t)(blk * 16 + r) * H_ + c0;
            float4 a = *(const float4*)(x + off);
            float4 b = *(const float4*)(x + off + 4);
            cs0 += a.x; cs1 += a.y; cs2 += a.z; cs3 += a.w;
            cs4 += b.x; cs5 += b.y; cs6 += b.z; cs7 += b.w;
            uint4 hi, lo;
            pack_hilo8(a, b, &hi, &lo);
            *(uint4*)(xhi + off) = hi;
            *(uint4*)(xlo + off) = lo;
        }
        float* pr = partial + (size_t)blk * H_ + c0;
        pr[0] = cs0; pr[1] = cs1; pr[2] = cs2; pr[3] = cs3;
        pr[4] = cs4; pr[5] = cs5; pr[6] = cs6; pr[7] = cs7;
    } else if (blk < 1152) {
        size_t base = (size_t)(blk - 128) * 4096 + (size_t)tid * 16;
#pragma unroll
        for (int q = 0; q < 2; ++q) {
            size_t o = base + q * 8;
            float4 a = *(const float4*)(lw + o);
            float4 b = *(const float4*)(lw + o + 4);
            *(uint4*)(lwh + o) = pack_hi8(a, b);
        }
    } else if (blk < 1408) {
        size_t base = (size_t)(blk - 1152) * 4096 + (size_t)tid * 16;
#pragma unroll
        for (int q = 0; q < 2; ++q) {
            size_t o = base + q * 8;
            float4 a = *(const float4*)(sw1 + o);
            float4 b = *(const float4*)(sw1 + o + 4);
            uint4 hi, lo;
            pack_hilo8(a, b, &hi, &lo);
            *(uint4*)(swh + o) = hi;
            *(uint4*)(swl + o) = lo;
        }
    } else {
        const float* src; ushort* dst; int rel;
        if (blk < 1410)      { src = u4;   dst = ubh;            rel = blk - 1408; }
        else if (blk < 1416) { src = u12;  dst = ubh + 4 * H_;   rel = blk - 1410; }
        else if (blk < 1436) { src = u40;  dst = ubh + 16 * H_;  rel = blk - 1416; }
        else                 { src = u128; dst = ubh + 56 * H_;  rel = blk - 1436; }
        size_t base = (size_t)rel * 4096 + (size_t)tid * 16;
#pragma unroll
        for (int q = 0; q < 2; ++q) {
            size_t o = base + q * 8;
            float4 a = *(const float4*)(src + o);
            float4 b = *(const float4*)(src + o + 4);
            *(uint4*)(dst + o) = pack_hi8(a, b);
        }
    }
}

// ---------------------------------------------------------------------------
// pool_final: xp[b][col] = mean over S of x  (from 64 partials per b).
// ---------------------------------------------------------------------------
__global__ __launch_bounds__(256) void pool_final_kernel(
    const float* __restrict__ partial, float* __restrict__ xp) {
    int b = blockIdx.x >> 3, chunk = blockIdx.x & 7;
    int col = (chunk << 8) + threadIdx.x;
    float s = 0.f;
    for (int seg = 0; seg < 64; ++seg)
        s += partial[(size_t)(b * 64 + seg) * H_ + col];
    xp[b * H_ + col] = s * (1.0f / S_);
}

// ---------------------------------------------------------------------------
// decide_dots: 192 blocks, one dot-product output each.
// ---------------------------------------------------------------------------
__global__ __launch_bounds__(256) void decide_dots(
    const float* __restrict__ xp, const float* __restrict__ kpw,
    const float* __restrict__ cw1, float* __restrict__ dots) {
    __shared__ float red[4];
    int o = blockIdx.x, tid = threadIdx.x;
    const float* xr;
    const float* wr;
    if (o < 64) {
        xr = xp + (o >> 5) * H_;
        wr = kpw + (size_t)(o & 31) * H_;
    } else {
        int o2 = o - 64;
        xr = xp + (o2 >> 6) * H_;
        wr = cw1 + (size_t)(o2 & 63) * H_;
    }
    int k0 = tid << 3;
    float4 xa = *(const float4*)(xr + k0);
    float4 xb = *(const float4*)(xr + k0 + 4);
    float4 wa = *(const float4*)(wr + k0);
    float4 wb = *(const float4*)(wr + k0 + 4);
    float s = xa.x * wa.x + xa.y * wa.y + xa.z * wa.z + xa.w * wa.w
            + xb.x * wb.x + xb.y * wb.y + xb.z * wb.z + xb.w * wb.w;
    for (int off = 32; off > 0; off >>= 1) s += __shfl_down(s, off, 64);
    if ((tid & 63) == 0) red[tid >> 6] = s;
    __syncthreads();
    if (tid == 0) dots[o] = red[0] + red[1] + red[2] + red[3];
}

// ---------------------------------------------------------------------------
// decide_final: tiny serial tail (O(4K) FLOP), one block.
// flags: [0]=n_crit (memset) [1]=rank_idx [2]=hit [3]=best
// ---------------------------------------------------------------------------
__global__ __launch_bounds__(64) void decide_final(
    const float* __restrict__ dots, const float* __restrict__ ck,
    const float* __restrict__ cb1, const float* __restrict__ cw2,
    const float* __restrict__ cb2, int* __restrict__ flags) {
    __shared__ float qk_s[64], ce_s[128], sims_s[NC_], sc_s[8];
    __shared__ float qn_s;
    int tid = threadIdx.x;
    if (tid < 64) qk_s[tid] = dots[tid];
    if (tid < 64) {
        ce_s[tid]      = fmaxf(dots[64 + tid] + cb1[tid & 63], 0.f);
        ce_s[tid + 64] = fmaxf(dots[128 + tid] + cb1[tid & 63], 0.f);
    }
    __syncthreads();
    if (tid == 0) {
        for (int b = 0; b < B_; ++b) {
            float nn = 0.f;
            for (int d = 0; d < KD_; ++d) { float v = qk_s[b * KD_ + d]; nn += v * v; }
            float den = fmaxf(sqrtf(nn), 1e-8f);
            for (int d = 0; d < KD_; ++d) qk_s[b * KD_ + d] /= den;
        }
        float qn = 0.f;
        for (int i = 0; i < B_ * KD_; ++i) qn += qk_s[i] * qk_s[i];
        qn_s = fmaxf(sqrtf(qn), 1e-8f);
    }
    __syncthreads();
    if (tid < NC_) {
        float dot = 0.f, nn = 0.f;
        for (int i = 0; i < B_ * KD_; ++i) {
            float c = ck[tid * (B_ * KD_) + i];
            dot += c * qk_s[i]; nn += c * c;
        }
        sims_s[tid] = dot / (fmaxf(sqrtf(nn), 1e-8f) * qn_s);
    }
    if (tid >= 32 && tid < 40) {
        int p = tid - 32, b = p >> 2, o = p & 3;
        float v = cb2[o];
        for (int j = 0; j < 64; ++j) v += ce_s[b * 64 + j] * cw2[o * 64 + j];
        sc_s[p] = v;
    }
    __syncthreads();
    if (tid == 0) {
        float bestv = -1e30f; int best = 0;
        for (int n = 0; n < NC_; ++n)
            if (sims_s[n] > bestv) { bestv = sims_s[n]; best = n; }
        flags[2] = (bestv >= 0.95f) ? 1 : 0;
        flags[3] = best;
        float bs = -1e30f; int bi = 0;
        for (int p = 0; p < 8; ++p)
            if (sc_s[p] > bs) { bs = sc_s[p]; bi = p; }
        flags[1] = bi & 3;
    }
}

// ---------------------------------------------------------------------------
// big_gemm: fused scorer (split-bf16) + all-rank projections, m97-style:
// linear [128][32] LDS tiles staged via global_load_lds width-16 (no reg
// round-trip, no ds_write, no staging VALU). 2 barriers per K-step.
//   y<4 : Hp tiles = xh·swh + xh·swl + xl·swh   (3 MFMA)
//   y>=4: Pp tiles = xh·ubh                      (1 MFMA; ubh padded 256 rows)
// ---------------------------------------------------------------------------
__global__ __launch_bounds__(256) void big_gemm(
    const ushort* __restrict__ xhi, const ushort* __restrict__ xlo,
    const ushort* __restrict__ swh, const ushort* __restrict__ swl,
    const ushort* __restrict__ ubh,
    float* __restrict__ Hp, float* __restrict__ Pp) {
    __shared__ ushort Ah[128][32], Al[128][32], Bh[128][32], Bl[128][32];
    int m0 = blockIdx.x << 7;
    int ny = blockIdx.y;
    int kz = blockIdx.z;
    bool split = ny < 4;
    int tid = threadIdx.x;
    int lr = tid >> 2;              // staging row 0..63 (and +64)
    int lc = (tid & 3) << 3;        // staging col in ushorts: 0/8/16/24

    const ushort* a0p = xhi + (size_t)(m0 + lr) * H_ + lc;
    const ushort* a1p = a0p + (size_t)64 * H_;
    const ushort* l0p = xlo + (size_t)(m0 + lr) * H_ + lc;
    const ushort* l1p = l0p + (size_t)64 * H_;
    const ushort* b0p; const ushort* b1p;
    const ushort* c0p = l0p; const ushort* c1p = l1p;
    if (split) {
        b0p = swh + (size_t)(ny * 128 + lr) * H_ + lc;
        b1p = b0p + (size_t)64 * H_;
        c0p = swl + (size_t)(ny * 128 + lr) * H_ + lc;
        c1p = c0p + (size_t)64 * H_;
    } else {
        b0p = ubh + (size_t)((ny - 4) * 128 + lr) * H_ + lc;  // rows <256, padded
        b1p = b0p + (size_t)64 * H_;
    }
    ushort* Ad0 = &Ah[lr][lc];      ushort* Ad1 = &Ah[lr + 64][lc];
    ushort* Ld0 = &Al[lr][lc];      ushort* Ld1 = &Al[lr + 64][lc];
    ushort* Bd0 = &Bh[lr][lc];      ushort* Bd1 = &Bh[lr + 64][lc];
    ushort* Cd0 = &Bl[lr][lc];      ushort* Cd1 = &Bl[lr + 64][lc];

    int lane = tid & 63, w = tid >> 6;
    int wm = (w >> 1) << 6, wn = (w & 1) << 6;
    int fr = lane & 15, kb = (lane >> 4) << 3;

    f32x4 zero4 = {0.f, 0.f, 0.f, 0.f};
    f32x4 acc[4][4];
#pragma unroll
    for (int i = 0; i < 4; ++i)
#pragma unroll
        for (int j = 0; j < 4; ++j) acc[i][j] = zero4;

    int kbeg = kz << 10;
    for (int kt = 0; kt < 32; ++kt) {
        int k0 = kbeg + (kt << 5);
        gld16(a0p + k0, Ad0); gld16(a1p + k0, Ad1);
        gld16(b0p + k0, Bd0); gld16(b1p + k0, Bd1);
        if (split) {
            gld16(l0p + k0, Ld0); gld16(l1p + k0, Ld1);
            gld16(c0p + k0, Cd0); gld16(c1p + k0, Cd1);
        }
        __syncthreads();   // drains vmcnt -> tiles resident
        bf16x8 ah[4], bh4[4], al4[4], bl4[4];
#pragma unroll
        for (int mt = 0; mt < 4; ++mt)
            ah[mt] = *(const bf16x8*)&Ah[wm + (mt << 4) + fr][kb];
#pragma unroll
        for (int nt = 0; nt < 4; ++nt)
            bh4[nt] = *(const bf16x8*)&Bh[wn + (nt << 4) + fr][kb];
        if (split) {
#pragma unroll
            for (int mt = 0; mt < 4; ++mt)
                al4[mt] = *(const bf16x8*)&Al[wm + (mt << 4) + fr][kb];
#pragma unroll
            for (int nt = 0; nt < 4; ++nt)
                bl4[nt] = *(const bf16x8*)&Bl[wn + (nt << 4) + fr][kb];
        }
#pragma unroll
        for (int mt = 0; mt < 4; ++mt)
#pragma unroll
            for (int nt = 0; nt < 4; ++nt) {
                acc[mt][nt] = __builtin_amdgcn_mfma_f32_16x16x32_bf16(
                    ah[mt], bh4[nt], acc[mt][nt], 0, 0, 0);
                if (split) {
                    acc[mt][nt] = __builtin_amdgcn_mfma_f32_16x16x32_bf16(
                        ah[mt], bl4[nt], acc[mt][nt], 0, 0, 0);
                    acc[mt][nt] = __builtin_amdgcn_mfma_f32_16x16x32_bf16(
                        al4[mt], bh4[nt], acc[mt][nt], 0, 0, 0);
                }
            }
        __syncthreads();   // all reads done before next staging overwrites
    }

    int orr = (lane >> 4) << 2;
    if (split) {
        float* dst = Hp + (size_t)kz * M_ * F_;
#pragma unroll
        for (int mt = 0; mt < 4; ++mt)
#pragma unroll
            for (int r = 0; r < 4; ++r) {
                int m = m0 + wm + (mt << 4) + orr + r;
                float* cr = dst + (size_t)m * F_ + (ny << 7) + wn;
#pragma unroll
                for (int nt = 0; nt < 4; ++nt)
                    cr[(nt << 4) + fr] = acc[mt][nt][r];
            }
    } else {
        float* dst = Pp + (size_t)kz * M_ * LDP;
        int nb0 = (ny - 4) << 7;
#pragma unroll
        for (int mt = 0; mt < 4; ++mt)
#pragma unroll
            for (int r = 0; r < 4; ++r) {
                int m = m0 + wm + (mt << 4) + orr + r;
                float* cr = dst + (size_t)m * LDP;
#pragma unroll
                for (int nt = 0; nt < 4; ++nt) {
                    int c = nb0 + wn + (nt << 4) + fr;
                    if (c < NPROJ) cr[c] = acc[mt][nt][r];
                }
            }
    }
}

// ---------------------------------------------------------------------------
// route_kernel: token routing from Hp partials. 512 blocks, 1 wave/token.
// ---------------------------------------------------------------------------
__global__ __launch_bounds__(256) void route_kernel(
    const float* __restrict__ Hp, const float* __restrict__ sb1,
    const float* __restrict__ sw2, const float* __restrict__ sb2,
    const float* __restrict__ pos,
    int* __restrict__ flags, int* __restrict__ route, int* __restrict__ clist) {
    int tid = threadIdx.x;
    int m = (blockIdx.x << 2) + (tid >> 6);
    int lane = tid & 63;
    const float* h0 = Hp + (size_t)m * F_;
    const float* h1 = Hp + (size_t)M_ * F_ + (size_t)m * F_;
    float s = 0.f;
    for (int f = lane; f < F_; f += 64)
        s += fmaxf(h0[f] + h1[f] + sb1[f], 0.f) * sw2[f];
    for (int off = 32; off > 0; off >>= 1) s += __shfl_down(s, off, 64);
    if (lane == 0) {
        float content = s + sb2[0];
        int si = m & (S_ - 1);
        float imp = 1.0f / (1.0f + expf(-(content + 0.1f * pos[si])));
        if (si == 0 || si == S_ - 1) imp *= 2.0f;
        int rt = (imp > 0.8f) ? 0 : ((imp < 0.3f) ? 1 : 2);
        route[m] = rt;
        if (rt == 0) {
            int idx = atomicAdd(&flags[0], 1);
            clist[idx] = m;
        }
    }
}

// ---------------------------------------------------------------------------
// crit_gemm: gathered-row bf16 MFMA GEMM (m97-style staging),
// out[row] = x[row]@lw^T + lb.
// ---------------------------------------------------------------------------
__global__ __launch_bounds__(256) void crit_gemm(
    const ushort* __restrict__ xhi, const ushort* __restrict__ lwh,
    const float* __restrict__ lb, const int* __restrict__ clist,
    const int* __restrict__ flags, float* __restrict__ out) {
    __shared__ ushort Ah[128][32], Bh[128][32];
    int M = flags[0];
    int m0 = blockIdx.x << 7;
    if (m0 >= M) return;
    int n0 = blockIdx.y << 7;
    int tid = threadIdx.x;
    int lr = tid >> 2, lc = (tid & 3) << 3;

    int gm0 = m0 + lr, gm1 = m0 + lr + 64;
    int ar0 = clist[gm0 < M ? gm0 : (M - 1)];
    int ar1 = clist[gm1 < M ? gm1 : (M - 1)];
    const ushort* a0p = xhi + (size_t)ar0 * H_ + lc;
    const ushort* a1p = xhi + (size_t)ar1 * H_ + lc;
    const ushort* b0p = lwh + (size_t)(n0 + lr) * H_ + lc;
    const ushort* b1p = b0p + (size_t)64 * H_;
    ushort* Ad0 = &Ah[lr][lc];  ushort* Ad1 = &Ah[lr + 64][lc];
    ushort* Bd0 = &Bh[lr][lc];  ushort* Bd1 = &Bh[lr + 64][lc];

    int lane = tid & 63, w = tid >> 6;
    int wm = (w >> 1) << 6, wn = (w & 1) << 6;
    int fr = lane & 15, kb = (lane >> 4) << 3;

    f32x4 zero4 = {0.f, 0.f, 0.f, 0.f};
    f32x4 acc[4][4];
#pragma unroll
    for (int i = 0; i < 4; ++i)
#pragma unroll
        for (int j = 0; j < 4; ++j) acc[i][j] = zero4;

    for (int kt = 0; kt < 64; ++kt) {
        int k0 = kt << 5;
        gld16(a0p + k0, Ad0); gld16(a1p + k0, Ad1);
        gld16(b0p + k0, Bd0); gld16(b1p + k0, Bd1);
        __syncthreads();
        bf16x8 af[4], bf4[4];
#pragma unroll
        for (int mt = 0; mt < 4; ++mt)
            af[mt] = *(const bf16x8*)&Ah[wm + (mt << 4) + fr][kb];
#pragma unroll
        for (int nt = 0; nt < 4; ++nt)
            bf4[nt] = *(const bf16x8*)&Bh[wn + (nt << 4) + fr][kb];
#pragma unroll
        for (int mt = 0; mt < 4; ++mt)
#pragma unroll
            for (int nt = 0; nt < 4; ++nt)
                acc[mt][nt] = __builtin_amdgcn_mfma_f32_16x16x32_bf16(
                    af[mt], bf4[nt], acc[mt][nt], 0, 0, 0);
        __syncthreads();
    }

    int orr = (lane >> 4) << 2;
#pragma unroll
    for (int mt = 0; mt < 4; ++mt)
#pragma unroll
        for (int r = 0; r < 4; ++r) {
            int m = m0 + wm + (mt << 4) + orr + r;
            if (m < M) {
                float* cr = out + (size_t)clist[m] * H_;
#pragma unroll
                for (int nt = 0; nt < 4; ++nt) {
                    int c = n0 + wn + (nt << 4) + fr;
                    cr[c] = acc[mt][nt][r] + lb[c];
                }
            }
        }
}

// ---------------------------------------------------------------------------
// stage2: merged simple+normal epilogue, single pass over x/Pp.
// route==1: out = x + (hit ? cache_delta[best] : t4 @ v4^T)
// route==2: out = x + tr @ v_rank^T
// ---------------------------------------------------------------------------
__global__ __launch_bounds__(256) void stage2_kernel(
    const float* __restrict__ x, const float* __restrict__ Pp,
    const float* __restrict__ v4, const float* __restrict__ v12,
    const float* __restrict__ v40, const float* __restrict__ v128,
    const float* __restrict__ cd, const int* __restrict__ flags,
    const int* __restrict__ route, float* __restrict__ out) {
    __shared__ float TsR[16][132];
    __shared__ float Ts4[16][4];
    __shared__ int rt_s[16];
    int tid = threadIdx.x;
    int m0 = blockIdx.x << 4;

    if (tid < 16) rt_s[tid] = route[m0 + tid];
    int r = flags[1];
    const float* V = (r == 0) ? v4 : (r == 1) ? v12 : (r == 2) ? v40 : v128;
    int Kr  = (r == 0) ? 4 : (r == 1) ? 12 : (r == 2) ? 40 : 128;
    int off = (r == 0) ? 0 : (r == 1) ? 4  : (r == 2) ? 16 : 56;
    int hit = flags[2], best = flags[3];

    const float* Pp1 = Pp + (size_t)M_ * LDP;
    for (int idx = tid; idx < 16 * Kr; idx += 256) {
        int i = idx / Kr, j = idx - i * Kr;
        size_t o = (size_t)(m0 + i) * LDP + off + j;
        TsR[i][j] = Pp[o] + Pp1[o];
    }
    if (tid < 64) {
        int i = tid >> 2, j = tid & 3;
        size_t o = (size_t)(m0 + i) * LDP + j;
        Ts4[i][j] = Pp[o] + Pp1[o];
    }
    __syncthreads();
    bool any1 = false, any2 = false;
#pragma unroll
    for (int i = 0; i < 16; ++i) { any1 |= (rt_s[i] == 1); any2 |= (rt_s[i] == 2); }
    if (!any1 && !any2) return;
    bool need4 = any1 && !hit;

    for (int c = tid; c < H_; c += 256) {
        float aR[16];
#pragma unroll
        for (int i = 0; i < 16; ++i) aR[i] = 0.f;
        if (any2) {
            const float* vrow = V + (size_t)c * Kr;
            for (int j = 0; j < Kr; j += 4) {
                const float4 vv = *(const float4*)(vrow + j);
#pragma unroll
                for (int i = 0; i < 16; ++i) {
                    const float4 tv = *(const float4*)&TsR[i][j];
                    aR[i] += tv.x * vv.x + tv.y * vv.y + tv.z * vv.z + tv.w * vv.w;
                }
            }
        }
        float a4[16];
        if (need4) {
            const float4 vv = *(const float4*)(v4 + (size_t)c * 4);
#pragma unroll
            for (int i = 0; i < 16; ++i) {
                const float4 tv = *(const float4*)&Ts4[i][0];
                a4[i] = tv.x * vv.x + tv.y * vv.y + tv.z * vv.z + tv.w * vv.w;
            }
        }
#pragma unroll
        for (int i = 0; i < 16; ++i) {
            int rt = rt_s[i];
            if (rt == 0) continue;
            size_t o = (size_t)(m0 + i) * H_ + c;
            float upd;
            if (rt == 1)
                upd = hit ? cd[(size_t)best * (size_t)(M_ * H_) + o] : a4[i];
            else
                upd = aR[i];
            out[o] = x[o] + upd;
        }
    }
}

// ---------------------------------------------------------------------------
extern "C" void kernel_launch(void* const* d_in, const int* in_sizes, int n_in,
                              void* d_out, int out_size, void* d_ws, size_t ws_size,
                              hipStream_t stream) {
    const float* x    = (const float*)d_in[0];
    const float* sw1  = (const float*)d_in[1];
    const float* sb1  = (const float*)d_in[2];
    const float* sw2  = (const float*)d_in[3];
    const float* sb2  = (const float*)d_in[4];
    const float* pos  = (const float*)d_in[5];
    const float* kpw  = (const float*)d_in[6];
    const float* ck   = (const float*)d_in[7];
    const float* cd   = (const float*)d_in[8];
    const float* cw1  = (const float*)d_in[9];
    const float* cb1  = (const float*)d_in[10];
    const float* cw2  = (const float*)d_in[11];
    const float* cb2  = (const float*)d_in[12];
    const float* u4   = (const float*)d_in[13];
    const float* v4   = (const float*)d_in[14];
    const float* u12  = (const float*)d_in[15];
    const float* v12  = (const float*)d_in[16];
    const float* u40  = (const float*)d_in[17];
    const float* v40  = (const float*)d_in[18];
    const float* u128 = (const float*)d_in[19];
    const float* v128 = (const float*)d_in[20];
    const float* lw   = (const float*)d_in[21];
    const float* lb   = (const float*)d_in[22];
    float* out = (float*)d_out;

    // ---- workspace layout (~35 MB) ----
    ushort* xhi = (ushort*)d_ws;                       // [M,H]
    ushort* xlo = xhi + (size_t)M_ * H_;               // [M,H]
    ushort* lwh = xlo + (size_t)M_ * H_;               // [H,H]
    ushort* swh = lwh + (size_t)H_ * H_;               // [F,H]
    ushort* swl = swh + (size_t)F_ * H_;               // [F,H]
    ushort* ubh = swl + (size_t)F_ * H_;               // [256,H] (184 valid)
    float* fbase   = (float*)(ubh + (size_t)256 * H_);
    float* xp      = fbase;                            // [2,H]
    float* partial = xp + 2 * H_;                      // [128,H]
    float* Pp      = partial + 128 * H_;               // [2,M,LDP]
    float* dots    = Pp + 2 * (size_t)M_ * LDP;        // [192]
    int*   flags   = (int*)(dots + 256);
    int*   route   = flags + 8;                        // [M]
    int*   clist   = route + M_;                       // [M]
    // Hp [2][M][F] aliases d_out's first 8.39 MB: consumed by route_kernel
    // before any out row is written; every out element is then written by
    // exactly one of {crit_gemm, stage2 route1, stage2 route2}.
    float* Hp = out;

    hipMemsetAsync(flags, 0, sizeof(int), stream);   // n_crit = 0

    conv_kernel<<<1500, 256, 0, stream>>>(x, lw, sw1, u4, u12, u40, u128,
                                          xhi, xlo, lwh, swh, swl, ubh, partial);
    pool_final_kernel<<<16, 256, 0, stream>>>(partial, xp);
    decide_dots<<<192, 256, 0, stream>>>(xp, kpw, cw1, dots);
    decide_final<<<1, 64, 0, stream>>>(dots, ck, cb1, cw2, cb2, flags);
    big_gemm<<<dim3(16, 6, 2), 256, 0, stream>>>(xhi, xlo, swh, swl, ubh, Hp, Pp);
    route_kernel<<<512, 256, 0, stream>>>(Hp, sb1, sw2, sb2, pos,
                                          flags, route, clist);
    crit_gemm<<<dim3(16, 16), 256, 0, stream>>>(xhi, lwh, lb, clist, flags, out);
    stage2_kernel<<<128, 256, 0, stream>>>(x, Pp, v4, v12, v40, v128,
                                           cd, flags, route, out);
}

// Round 2
// 529.590 us; speedup vs baseline: 1.2216x; 1.2216x over previous
//
#include <hip/hip_runtime.h>
#include <math.h>

#define B_  2
#define S_  1024
#define H_  2048
#define F_  512          // H/4
#define KD_ 32
#define NC_ 16
#define M_  2048         // B*S tokens
#define NPROJ 184        // 4+12+40+128 packed u-rows
#define LDP 192          // proj row stride

typedef __attribute__((ext_vector_type(8))) short bf16x8;
typedef __attribute__((ext_vector_type(4))) float f32x4;

typedef __attribute__((address_space(1))) const void gvoid_t;
typedef __attribute__((address_space(3))) void lvoid_t;

// async global -> LDS, 16B per lane. LDS dest must be wave-uniform base + lane*16.
__device__ __forceinline__ void gld16(const void* g, void* l) {
    __builtin_amdgcn_global_load_lds((gvoid_t*)g, (lvoid_t*)l, 16, 0, 0);
}

__device__ __forceinline__ ushort f2bf(float f) {
    unsigned u = __float_as_uint(f);
    u += 0x7FFFu + ((u >> 16) & 1u);   // RNE
    return (ushort)(u >> 16);
}
__device__ __forceinline__ float bf2f(ushort h) {
    return __uint_as_float(((unsigned)h) << 16);
}
__device__ __forceinline__ uint4 pack_hi8(float4 a, float4 b) {
    uint4 r;
    r.x = (unsigned)f2bf(a.x) | ((unsigned)f2bf(a.y) << 16);
    r.y = (unsigned)f2bf(a.z) | ((unsigned)f2bf(a.w) << 16);
    r.z = (unsigned)f2bf(b.x) | ((unsigned)f2bf(b.y) << 16);
    r.w = (unsigned)f2bf(b.z) | ((unsigned)f2bf(b.w) << 16);
    return r;
}
__device__ __forceinline__ void pack_hilo8(float4 a, float4 b, uint4* hi, uint4* lo) {
    float v[8] = {a.x, a.y, a.z, a.w, b.x, b.y, b.z, b.w};
    unsigned h[8], l[8];
#pragma unroll
    for (int i = 0; i < 8; ++i) {
        ushort hh = f2bf(v[i]);
        h[i] = hh;
        l[i] = f2bf(v[i] - bf2f(hh));
    }
    *hi = make_uint4(h[0] | (h[1] << 16), h[2] | (h[3] << 16),
                     h[4] | (h[5] << 16), h[6] | (h[7] << 16));
    *lo = make_uint4(l[0] | (l[1] << 16), l[2] | (l[3] << 16),
                     l[4] | (l[5] << 16), l[6] | (l[7] << 16));
}

// ---------------------------------------------------------------------------
// conv_kernel: bf16 conversions + pool partials, one pass.
// blocks 0..127    : x rows blk*16..+16 -> xhi,xlo + column-sum partial[blk]
// blocks 128..1151 : lw (flat, hi only)
// blocks 1152..1407: sw1 (flat, hi+lo)
// blocks 1408..1499: u4|u12|u40|u128 -> packed ubh rows {0,4,16,56}
// ---------------------------------------------------------------------------
__global__ __launch_bounds__(256) void conv_kernel(
    const float* __restrict__ x, const float* __restrict__ lw,
    const float* __restrict__ sw1,
    const float* __restrict__ u4, const float* __restrict__ u12,
    const float* __restrict__ u40, const float* __restrict__ u128,
    ushort* __restrict__ xhi, ushort* __restrict__ xlo,
    ushort* __restrict__ lwh, ushort* __restrict__ swh,
    ushort* __restrict__ swl, ushort* __restrict__ ubh,
    float* __restrict__ partial) {
    int blk = blockIdx.x, tid = threadIdx.x;
    if (blk < 128) {
        int c0 = tid << 3;
        float cs0 = 0.f, cs1 = 0.f, cs2 = 0.f, cs3 = 0.f;
        float cs4 = 0.f, cs5 = 0.f, cs6 = 0.f, cs7 = 0.f;
        for (int r = 0; r < 16; ++r) {
            size_t off = (size_t)(blk * 16 + r) * H_ + c0;
            float4 a = *(const float4*)(x + off);
            float4 b = *(const float4*)(x + off + 4);
            cs0 += a.x; cs1 += a.y; cs2 += a.z; cs3 += a.w;
            cs4 += b.x; cs5 += b.y; cs6 += b.z; cs7 += b.w;
            uint4 hi, lo;
            pack_hilo8(a, b, &hi, &lo);
            *(uint4*)(xhi + off) = hi;
            *(uint4*)(xlo + off) = lo;
        }
        float* pr = partial + (size_t)blk * H_ + c0;
        pr[0] = cs0; pr[1] = cs1; pr[2] = cs2; pr[3] = cs3;
        pr[4] = cs4; pr[5] = cs5; pr[6] = cs6; pr[7] = cs7;
    } else if (blk < 1152) {
        size_t base = (size_t)(blk - 128) * 4096 + (size_t)tid * 16;
#pragma unroll
        for (int q = 0; q < 2; ++q) {
            size_t o = base + q * 8;
            float4 a = *(const float4*)(lw + o);
            float4 b = *(const float4*)(lw + o + 4);
            *(uint4*)(lwh + o) = pack_hi8(a, b);
        }
    } else if (blk < 1408) {
        size_t base = (size_t)(blk - 1152) * 4096 + (size_t)tid * 16;
#pragma unroll
        for (int q = 0; q < 2; ++q) {
            size_t o = base + q * 8;
            float4 a = *(const float4*)(sw1 + o);
            float4 b = *(const float4*)(sw1 + o + 4);
            uint4 hi, lo;
            pack_hilo8(a, b, &hi, &lo);
            *(uint4*)(swh + o) = hi;
            *(uint4*)(swl + o) = lo;
        }
    } else {
        const float* src; ushort* dst; int rel;
        if (blk < 1410)      { src = u4;   dst = ubh;            rel = blk - 1408; }
        else if (blk < 1416) { src = u12;  dst = ubh + 4 * H_;   rel = blk - 1410; }
        else if (blk < 1436) { src = u40;  dst = ubh + 16 * H_;  rel = blk - 1416; }
        else                 { src = u128; dst = ubh + 56 * H_;  rel = blk - 1436; }
        size_t base = (size_t)rel * 4096 + (size_t)tid * 16;
#pragma unroll
        for (int q = 0; q < 2; ++q) {
            size_t o = base + q * 8;
            float4 a = *(const float4*)(src + o);
            float4 b = *(const float4*)(src + o + 4);
            *(uint4*)(dst + o) = pack_hi8(a, b);
        }
    }
}

// ---------------------------------------------------------------------------
// pool_final: xp[b][col] = mean over S of x  (from 64 partials per b).
// ---------------------------------------------------------------------------
__global__ __launch_bounds__(256) void pool_final_kernel(
    const float* __restrict__ partial, float* __restrict__ xp) {
    int b = blockIdx.x >> 3, chunk = blockIdx.x & 7;
    int col = (chunk << 8) + threadIdx.x;
    float s = 0.f;
    for (int seg = 0; seg < 64; ++seg)
        s += partial[(size_t)(b * 64 + seg) * H_ + col];
    xp[b * H_ + col] = s * (1.0f / S_);
}

// ---------------------------------------------------------------------------
// decide_dots: 192 blocks, one dot-product output each.
// ---------------------------------------------------------------------------
__global__ __launch_bounds__(256) void decide_dots(
    const float* __restrict__ xp, const float* __restrict__ kpw,
    const float* __restrict__ cw1, float* __restrict__ dots) {
    __shared__ float red[4];
    int o = blockIdx.x, tid = threadIdx.x;
    const float* xr;
    const float* wr;
    if (o < 64) {
        xr = xp + (o >> 5) * H_;
        wr = kpw + (size_t)(o & 31) * H_;
    } else {
        int o2 = o - 64;
        xr = xp + (o2 >> 6) * H_;
        wr = cw1 + (size_t)(o2 & 63) * H_;
    }
    int k0 = tid << 3;
    float4 xa = *(const float4*)(xr + k0);
    float4 xb = *(const float4*)(xr + k0 + 4);
    float4 wa = *(const float4*)(wr + k0);
    float4 wb = *(const float4*)(wr + k0 + 4);
    float s = xa.x * wa.x + xa.y * wa.y + xa.z * wa.z + xa.w * wa.w
            + xb.x * wb.x + xb.y * wb.y + xb.z * wb.z + xb.w * wb.w;
    for (int off = 32; off > 0; off >>= 1) s += __shfl_down(s, off, 64);
    if ((tid & 63) == 0) red[tid >> 6] = s;
    __syncthreads();
    if (tid == 0) dots[o] = red[0] + red[1] + red[2] + red[3];
}

// ---------------------------------------------------------------------------
// decide_final: tiny serial tail (O(4K) FLOP), one block.
// flags: [0]=n_crit (memset) [1]=rank_idx [2]=hit [3]=best
// ---------------------------------------------------------------------------
__global__ __launch_bounds__(64) void decide_final(
    const float* __restrict__ dots, const float* __restrict__ ck,
    const float* __restrict__ cb1, const float* __restrict__ cw2,
    const float* __restrict__ cb2, int* __restrict__ flags) {
    __shared__ float qk_s[64], ce_s[128], sims_s[NC_], sc_s[8];
    __shared__ float qn_s;
    int tid = threadIdx.x;
    if (tid < 64) qk_s[tid] = dots[tid];
    if (tid < 64) {
        ce_s[tid]      = fmaxf(dots[64 + tid] + cb1[tid & 63], 0.f);
        ce_s[tid + 64] = fmaxf(dots[128 + tid] + cb1[tid & 63], 0.f);
    }
    __syncthreads();
    if (tid == 0) {
        for (int b = 0; b < B_; ++b) {
            float nn = 0.f;
            for (int d = 0; d < KD_; ++d) { float v = qk_s[b * KD_ + d]; nn += v * v; }
            float den = fmaxf(sqrtf(nn), 1e-8f);
            for (int d = 0; d < KD_; ++d) qk_s[b * KD_ + d] /= den;
        }
        float qn = 0.f;
        for (int i = 0; i < B_ * KD_; ++i) qn += qk_s[i] * qk_s[i];
        qn_s = fmaxf(sqrtf(qn), 1e-8f);
    }
    __syncthreads();
    if (tid < NC_) {
        float dot = 0.f, nn = 0.f;
        for (int i = 0; i < B_ * KD_; ++i) {
            float c = ck[tid * (B_ * KD_) + i];
            dot += c * qk_s[i]; nn += c * c;
        }
        sims_s[tid] = dot / (fmaxf(sqrtf(nn), 1e-8f) * qn_s);
    }
    if (tid >= 32 && tid < 40) {
        int p = tid - 32, b = p >> 2, o = p & 3;
        float v = cb2[o];
        for (int j = 0; j < 64; ++j) v += ce_s[b * 64 + j] * cw2[o * 64 + j];
        sc_s[p] = v;
    }
    __syncthreads();
    if (tid == 0) {
        float bestv = -1e30f; int best = 0;
        for (int n = 0; n < NC_; ++n)
            if (sims_s[n] > bestv) { bestv = sims_s[n]; best = n; }
        flags[2] = (bestv >= 0.95f) ? 1 : 0;
        flags[3] = best;
        float bs = -1e30f; int bi = 0;
        for (int p = 0; p < 8; ++p)
            if (sc_s[p] > bs) { bs = sc_s[p]; bi = p; }
        flags[1] = bi & 3;
    }
}

// ---------------------------------------------------------------------------
// big_gemm: fused scorer (split-bf16) + all-rank projections, m97-style:
// linear [128][32] LDS tiles staged via global_load_lds width-16.
//   y<4 : Hp tiles = xh·swh + xh·swl + xl·swh   (3 MFMA)
//   y>=4: Pp tiles = xh·ubh                      (1 MFMA; ubh padded 256 rows)
// ---------------------------------------------------------------------------
__global__ __launch_bounds__(256) void big_gemm(
    const ushort* __restrict__ xhi, const ushort* __restrict__ xlo,
    const ushort* __restrict__ swh, const ushort* __restrict__ swl,
    const ushort* __restrict__ ubh,
    float* __restrict__ Hp, float* __restrict__ Pp) {
    __shared__ ushort Ah[128][32], Al[128][32], Bh[128][32], Bl[128][32];
    int m0 = blockIdx.x << 7;
    int ny = blockIdx.y;
    int kz = blockIdx.z;
    bool split = ny < 4;
    int tid = threadIdx.x;
    int lr = tid >> 2;              // staging row 0..63 (and +64)
    int lc = (tid & 3) << 3;        // staging col in ushorts: 0/8/16/24

    const ushort* a0p = xhi + (size_t)(m0 + lr) * H_ + lc;
    const ushort* a1p = a0p + (size_t)64 * H_;
    const ushort* l0p = xlo + (size_t)(m0 + lr) * H_ + lc;
    const ushort* l1p = l0p + (size_t)64 * H_;
    const ushort* b0p; const ushort* b1p;
    const ushort* c0p = l0p; const ushort* c1p = l1p;
    if (split) {
        b0p = swh + (size_t)(ny * 128 + lr) * H_ + lc;
        b1p = b0p + (size_t)64 * H_;
        c0p = swl + (size_t)(ny * 128 + lr) * H_ + lc;
        c1p = c0p + (size_t)64 * H_;
    } else {
        b0p = ubh + (size_t)((ny - 4) * 128 + lr) * H_ + lc;  // rows <256, padded
        b1p = b0p + (size_t)64 * H_;
    }
    ushort* Ad0 = &Ah[lr][lc];      ushort* Ad1 = &Ah[lr + 64][lc];
    ushort* Ld0 = &Al[lr][lc];      ushort* Ld1 = &Al[lr + 64][lc];
    ushort* Bd0 = &Bh[lr][lc];      ushort* Bd1 = &Bh[lr + 64][lc];
    ushort* Cd0 = &Bl[lr][lc];      ushort* Cd1 = &Bl[lr + 64][lc];

    int lane = tid & 63, w = tid >> 6;
    int wm = (w >> 1) << 6, wn = (w & 1) << 6;
    int fr = lane & 15, kb = (lane >> 4) << 3;

    f32x4 zero4 = {0.f, 0.f, 0.f, 0.f};
    f32x4 acc[4][4];
#pragma unroll
    for (int i = 0; i < 4; ++i)
#pragma unroll
        for (int j = 0; j < 4; ++j) acc[i][j] = zero4;

    int kbeg = kz << 10;
    for (int kt = 0; kt < 32; ++kt) {
        int k0 = kbeg + (kt << 5);
        gld16(a0p + k0, Ad0); gld16(a1p + k0, Ad1);
        gld16(b0p + k0, Bd0); gld16(b1p + k0, Bd1);
        if (split) {
            gld16(l0p + k0, Ld0); gld16(l1p + k0, Ld1);
            gld16(c0p + k0, Cd0); gld16(c1p + k0, Cd1);
        }
        __syncthreads();   // drains vmcnt -> tiles resident
        bf16x8 ah[4], bh4[4], al4[4], bl4[4];
#pragma unroll
        for (int mt = 0; mt < 4; ++mt)
            ah[mt] = *(const bf16x8*)&Ah[wm + (mt << 4) + fr][kb];
#pragma unroll
        for (int nt = 0; nt < 4; ++nt)
            bh4[nt] = *(const bf16x8*)&Bh[wn + (nt << 4) + fr][kb];
        if (split) {
#pragma unroll
            for (int mt = 0; mt < 4; ++mt)
                al4[mt] = *(const bf16x8*)&Al[wm + (mt << 4) + fr][kb];
#pragma unroll
            for (int nt = 0; nt < 4; ++nt)
                bl4[nt] = *(const bf16x8*)&Bl[wn + (nt << 4) + fr][kb];
        }
#pragma unroll
        for (int mt = 0; mt < 4; ++mt)
#pragma unroll
            for (int nt = 0; nt < 4; ++nt) {
                acc[mt][nt] = __builtin_amdgcn_mfma_f32_16x16x32_bf16(
                    ah[mt], bh4[nt], acc[mt][nt], 0, 0, 0);
                if (split) {
                    acc[mt][nt] = __builtin_amdgcn_mfma_f32_16x16x32_bf16(
                        ah[mt], bl4[nt], acc[mt][nt], 0, 0, 0);
                    acc[mt][nt] = __builtin_amdgcn_mfma_f32_16x16x32_bf16(
                        al4[mt], bh4[nt], acc[mt][nt], 0, 0, 0);
                }
            }
        __syncthreads();   // all reads done before next staging overwrites
    }

    int orr = (lane >> 4) << 2;
    if (split) {
        float* dst = Hp + (size_t)kz * M_ * F_;
#pragma unroll
        for (int mt = 0; mt < 4; ++mt)
#pragma unroll
            for (int r = 0; r < 4; ++r) {
                int m = m0 + wm + (mt << 4) + orr + r;
                float* cr = dst + (size_t)m * F_ + (ny << 7) + wn;
#pragma unroll
                for (int nt = 0; nt < 4; ++nt)
                    cr[(nt << 4) + fr] = acc[mt][nt][r];
            }
    } else {
        float* dst = Pp + (size_t)kz * M_ * LDP;
        int nb0 = (ny - 4) << 7;
#pragma unroll
        for (int mt = 0; mt < 4; ++mt)
#pragma unroll
            for (int r = 0; r < 4; ++r) {
                int m = m0 + wm + (mt << 4) + orr + r;
                float* cr = dst + (size_t)m * LDP;
#pragma unroll
                for (int nt = 0; nt < 4; ++nt) {
                    int c = nb0 + wn + (nt << 4) + fr;
                    if (c < NPROJ) cr[c] = acc[mt][nt][r];
                }
            }
    }
}

// ---------------------------------------------------------------------------
// route_kernel: token routing from Hp partials. 512 blocks, 1 wave/token.
// ---------------------------------------------------------------------------
__global__ __launch_bounds__(256) void route_kernel(
    const float* __restrict__ Hp, const float* __restrict__ sb1,
    const float* __restrict__ sw2, const float* __restrict__ sb2,
    const float* __restrict__ pos,
    int* __restrict__ flags, int* __restrict__ route, int* __restrict__ clist) {
    int tid = threadIdx.x;
    int m = (blockIdx.x << 2) + (tid >> 6);
    int lane = tid & 63;
    const float* h0 = Hp + (size_t)m * F_;
    const float* h1 = Hp + (size_t)M_ * F_ + (size_t)m * F_;
    float s = 0.f;
    for (int f = lane; f < F_; f += 64)
        s += fmaxf(h0[f] + h1[f] + sb1[f], 0.f) * sw2[f];
    for (int off = 32; off > 0; off >>= 1) s += __shfl_down(s, off, 64);
    if (lane == 0) {
        float content = s + sb2[0];
        int si = m & (S_ - 1);
        float imp = 1.0f / (1.0f + expf(-(content + 0.1f * pos[si])));
        if (si == 0 || si == S_ - 1) imp *= 2.0f;
        int rt = (imp > 0.8f) ? 0 : ((imp < 0.3f) ? 1 : 2);
        route[m] = rt;
        if (rt == 0) {
            int idx = atomicAdd(&flags[0], 1);
            clist[idx] = m;
        }
    }
}

// ---------------------------------------------------------------------------
// crit_gemm: gathered-row bf16 MFMA GEMM (m97-style staging),
// out[row] = x[row]@lw^T + lb.
// ---------------------------------------------------------------------------
__global__ __launch_bounds__(256) void crit_gemm(
    const ushort* __restrict__ xhi, const ushort* __restrict__ lwh,
    const float* __restrict__ lb, const int* __restrict__ clist,
    const int* __restrict__ flags, float* __restrict__ out) {
    __shared__ ushort Ah[128][32], Bh[128][32];
    int M = flags[0];
    int m0 = blockIdx.x << 7;
    if (m0 >= M) return;
    int n0 = blockIdx.y << 7;
    int tid = threadIdx.x;
    int lr = tid >> 2, lc = (tid & 3) << 3;

    int gm0 = m0 + lr, gm1 = m0 + lr + 64;
    int ar0 = clist[gm0 < M ? gm0 : (M - 1)];
    int ar1 = clist[gm1 < M ? gm1 : (M - 1)];
    const ushort* a0p = xhi + (size_t)ar0 * H_ + lc;
    const ushort* a1p = xhi + (size_t)ar1 * H_ + lc;
    const ushort* b0p = lwh + (size_t)(n0 + lr) * H_ + lc;
    const ushort* b1p = b0p + (size_t)64 * H_;
    ushort* Ad0 = &Ah[lr][lc];  ushort* Ad1 = &Ah[lr + 64][lc];
    ushort* Bd0 = &Bh[lr][lc];  ushort* Bd1 = &Bh[lr + 64][lc];

    int lane = tid & 63, w = tid >> 6;
    int wm = (w >> 1) << 6, wn = (w & 1) << 6;
    int fr = lane & 15, kb = (lane >> 4) << 3;

    f32x4 zero4 = {0.f, 0.f, 0.f, 0.f};
    f32x4 acc[4][4];
#pragma unroll
    for (int i = 0; i < 4; ++i)
#pragma unroll
        for (int j = 0; j < 4; ++j) acc[i][j] = zero4;

    for (int kt = 0; kt < 64; ++kt) {
        int k0 = kt << 5;
        gld16(a0p + k0, Ad0); gld16(a1p + k0, Ad1);
        gld16(b0p + k0, Bd0); gld16(b1p + k0, Bd1);
        __syncthreads();
        bf16x8 af[4], bf4[4];
#pragma unroll
        for (int mt = 0; mt < 4; ++mt)
            af[mt] = *(const bf16x8*)&Ah[wm + (mt << 4) + fr][kb];
#pragma unroll
        for (int nt = 0; nt < 4; ++nt)
            bf4[nt] = *(const bf16x8*)&Bh[wn + (nt << 4) + fr][kb];
#pragma unroll
        for (int mt = 0; mt < 4; ++mt)
#pragma unroll
            for (int nt = 0; nt < 4; ++nt)
                acc[mt][nt] = __builtin_amdgcn_mfma_f32_16x16x32_bf16(
                    af[mt], bf4[nt], acc[mt][nt], 0, 0, 0);
        __syncthreads();
    }

    int orr = (lane >> 4) << 2;
#pragma unroll
    for (int mt = 0; mt < 4; ++mt)
#pragma unroll
        for (int r = 0; r < 4; ++r) {
            int m = m0 + wm + (mt << 4) + orr + r;
            if (m < M) {
                float* cr = out + (size_t)clist[m] * H_;
#pragma unroll
                for (int nt = 0; nt < 4; ++nt) {
                    int c = n0 + wn + (nt << 4) + fr;
                    cr[c] = acc[mt][nt][r] + lb[c];
                }
            }
        }
}

// ---------------------------------------------------------------------------
// stage2: merged simple+normal epilogue, column-split for occupancy.
// grid = 128 m-chunks x 16 col-chunks = 2048 blocks (8/CU).
// Each block: 16 tokens x 128 columns.
// route==1: out = x + (hit ? cache_delta[best] : t4 @ v4^T)
// route==2: out = x + tr @ v_rank^T
// ---------------------------------------------------------------------------
__global__ __launch_bounds__(256) void stage2_kernel(
    const float* __restrict__ x, const float* __restrict__ Pp,
    const float* __restrict__ v4, const float* __restrict__ v12,
    const float* __restrict__ v40, const float* __restrict__ v128,
    const float* __restrict__ cd, const int* __restrict__ flags,
    const int* __restrict__ route, float* __restrict__ out) {
    __shared__ float TsR[16][132];
    __shared__ float Ts4[16][4];
    __shared__ int rt_s[16];
    int tid = threadIdx.x;
    int m0 = (blockIdx.x >> 4) << 4;       // token chunk
    int c0 = (blockIdx.x & 15) << 7;       // column chunk (128 cols)

    if (tid < 16) rt_s[tid] = route[m0 + tid];
    int r = flags[1];
    const float* V = (r == 0) ? v4 : (r == 1) ? v12 : (r == 2) ? v40 : v128;
    int Kr  = (r == 0) ? 4 : (r == 1) ? 12 : (r == 2) ? 40 : 128;
    int off = (r == 0) ? 0 : (r == 1) ? 4  : (r == 2) ? 16 : 56;
    int hit = flags[2], best = flags[3];

    const float* Pp1 = Pp + (size_t)M_ * LDP;
    for (int idx = tid; idx < 16 * Kr; idx += 256) {
        int i = idx / Kr, j = idx - i * Kr;
        size_t o = (size_t)(m0 + i) * LDP + off + j;
        TsR[i][j] = Pp[o] + Pp1[o];
    }
    if (tid < 64) {
        int i = tid >> 2, j = tid & 3;
        size_t o = (size_t)(m0 + i) * LDP + j;
        Ts4[i][j] = Pp[o] + Pp1[o];
    }
    __syncthreads();
    bool any1 = false, any2 = false;
#pragma unroll
    for (int i = 0; i < 16; ++i) { any1 |= (rt_s[i] == 1); any2 |= (rt_s[i] == 2); }
    if (!any1 && !any2) return;
    bool need4 = any1 && !hit;

    int c = c0 + (tid & 127);
    int i0 = (tid >> 7) << 3;              // 0 or 8: token half per wave-pair

    float aR[8];
#pragma unroll
    for (int i = 0; i < 8; ++i) aR[i] = 0.f;
    if (any2) {
        const float* vrow = V + (size_t)c * Kr;
        for (int j = 0; j < Kr; j += 4) {
            const float4 vv = *(const float4*)(vrow + j);
#pragma unroll
            for (int i = 0; i < 8; ++i) {
                const float4 tv = *(const float4*)&TsR[i0 + i][j];
                aR[i] += tv.x * vv.x + tv.y * vv.y + tv.z * vv.z + tv.w * vv.w;
            }
        }
    }
    float a4[8];
    if (need4) {
        const float4 vv = *(const float4*)(v4 + (size_t)c * 4);
#pragma unroll
        for (int i = 0; i < 8; ++i) {
            const float4 tv = *(const float4*)&Ts4[i0 + i][0];
            a4[i] = tv.x * vv.x + tv.y * vv.y + tv.z * vv.z + tv.w * vv.w;
        }
    }
#pragma unroll
    for (int i = 0; i < 8; ++i) {
        int rt = rt_s[i0 + i];
        if (rt == 0) continue;
        size_t o = (size_t)(m0 + i0 + i) * H_ + c;
        float upd;
        if (rt == 1)
            upd = hit ? cd[(size_t)best * (size_t)(M_ * H_) + o] : a4[i];
        else
            upd = aR[i];
        out[o] = x[o] + upd;
    }
}

// ---------------------------------------------------------------------------
extern "C" void kernel_launch(void* const* d_in, const int* in_sizes, int n_in,
                              void* d_out, int out_size, void* d_ws, size_t ws_size,
                              hipStream_t stream) {
    const float* x    = (const float*)d_in[0];
    const float* sw1  = (const float*)d_in[1];
    const float* sb1  = (const float*)d_in[2];
    const float* sw2  = (const float*)d_in[3];
    const float* sb2  = (const float*)d_in[4];
    const float* pos  = (const float*)d_in[5];
    const float* kpw  = (const float*)d_in[6];
    const float* ck   = (const float*)d_in[7];
    const float* cd   = (const float*)d_in[8];
    const float* cw1  = (const float*)d_in[9];
    const float* cb1  = (const float*)d_in[10];
    const float* cw2  = (const float*)d_in[11];
    const float* cb2  = (const float*)d_in[12];
    const float* u4   = (const float*)d_in[13];
    const float* v4   = (const float*)d_in[14];
    const float* u12  = (const float*)d_in[15];
    const float* v12  = (const float*)d_in[16];
    const float* u40  = (const float*)d_in[17];
    const float* v40  = (const float*)d_in[18];
    const float* u128 = (const float*)d_in[19];
    const float* v128 = (const float*)d_in[20];
    const float* lw   = (const float*)d_in[21];
    const float* lb   = (const float*)d_in[22];
    float* out = (float*)d_out;

    // ---- workspace layout (~35 MB) ----
    ushort* xhi = (ushort*)d_ws;                       // [M,H]
    ushort* xlo = xhi + (size_t)M_ * H_;               // [M,H]
    ushort* lwh = xlo + (size_t)M_ * H_;               // [H,H]
    ushort* swh = lwh + (size_t)H_ * H_;               // [F,H]
    ushort* swl = swh + (size_t)F_ * H_;               // [F,H]
    ushort* ubh = swl + (size_t)F_ * H_;               // [256,H] (184 valid)
    float* fbase   = (float*)(ubh + (size_t)256 * H_);
    float* xp      = fbase;                            // [2,H]
    float* partial = xp + 2 * H_;                      // [128,H]
    float* Pp      = partial + 128 * H_;               // [2,M,LDP]
    float* dots    = Pp + 2 * (size_t)M_ * LDP;        // [192]
    int*   flags   = (int*)(dots + 256);
    int*   route   = flags + 8;                        // [M]
    int*   clist   = route + M_;                       // [M]
    // Hp [2][M][F] aliases d_out's first 8.39 MB: consumed by route_kernel
    // before any out row is written; every out element is then written by
    // exactly one of {crit_gemm, stage2 route1, stage2 route2}.
    float* Hp = out;

    hipMemsetAsync(flags, 0, sizeof(int), stream);   // n_crit = 0

    conv_kernel<<<1500, 256, 0, stream>>>(x, lw, sw1, u4, u12, u40, u128,
                                          xhi, xlo, lwh, swh, swl, ubh, partial);
    pool_final_kernel<<<16, 256, 0, stream>>>(partial, xp);
    decide_dots<<<192, 256, 0, stream>>>(xp, kpw, cw1, dots);
    decide_final<<<1, 64, 0, stream>>>(dots, ck, cb1, cw2, cb2, flags);
    big_gemm<<<dim3(16, 6, 2), 256, 0, stream>>>(xhi, xlo, swh, swl, ubh, Hp, Pp);
    route_kernel<<<512, 256, 0, stream>>>(Hp, sb1, sw2, sb2, pos,
                                          flags, route, clist);
    crit_gemm<<<dim3(16, 16), 256, 0, stream>>>(xhi, lwh, lb, clist, flags, out);
    stage2_kernel<<<2048, 256, 0, stream>>>(x, Pp, v4, v12, v40, v128,
                                            cd, flags, route, out);
}

// Round 3
// 519.044 us; speedup vs baseline: 1.2464x; 1.0203x over previous
//
#include <hip/hip_runtime.h>
#include <math.h>

#define B_  2
#define S_  1024
#define H_  2048
#define F_  512          // H/4
#define KD_ 32
#define NC_ 16
#define M_  2048         // B*S tokens
#define NPROJ 184        // 4+12+40+128 packed u-rows
#define LDP 192          // proj row stride
#define KZ_ 4            // K-split factor for big_gemm

typedef __attribute__((ext_vector_type(8))) short bf16x8;
typedef __attribute__((ext_vector_type(4))) float f32x4;

typedef __attribute__((address_space(1))) const void gvoid_t;
typedef __attribute__((address_space(3))) void lvoid_t;

// async global -> LDS, 16B per lane. LDS dest must be wave-uniform base + lane*16.
__device__ __forceinline__ void gld16(const void* g, void* l) {
    __builtin_amdgcn_global_load_lds((gvoid_t*)g, (lvoid_t*)l, 16, 0, 0);
}

__device__ __forceinline__ ushort f2bf(float f) {
    unsigned u = __float_as_uint(f);
    u += 0x7FFFu + ((u >> 16) & 1u);   // RNE
    return (ushort)(u >> 16);
}
__device__ __forceinline__ float bf2f(ushort h) {
    return __uint_as_float(((unsigned)h) << 16);
}
__device__ __forceinline__ uint4 pack_hi8(float4 a, float4 b) {
    uint4 r;
    r.x = (unsigned)f2bf(a.x) | ((unsigned)f2bf(a.y) << 16);
    r.y = (unsigned)f2bf(a.z) | ((unsigned)f2bf(a.w) << 16);
    r.z = (unsigned)f2bf(b.x) | ((unsigned)f2bf(b.y) << 16);
    r.w = (unsigned)f2bf(b.z) | ((unsigned)f2bf(b.w) << 16);
    return r;
}
__device__ __forceinline__ void pack_hilo8(float4 a, float4 b, uint4* hi, uint4* lo) {
    float v[8] = {a.x, a.y, a.z, a.w, b.x, b.y, b.z, b.w};
    unsigned h[8], l[8];
#pragma unroll
    for (int i = 0; i < 8; ++i) {
        ushort hh = f2bf(v[i]);
        h[i] = hh;
        l[i] = f2bf(v[i] - bf2f(hh));
    }
    *hi = make_uint4(h[0] | (h[1] << 16), h[2] | (h[3] << 16),
                     h[4] | (h[5] << 16), h[6] | (h[7] << 16));
    *lo = make_uint4(l[0] | (l[1] << 16), l[2] | (l[3] << 16),
                     l[4] | (l[5] << 16), l[6] | (l[7] << 16));
}

// ---------------------------------------------------------------------------
// conv_kernel: bf16 conversions + pool partials, one pass.
// blocks 0..127    : x rows blk*16..+16 -> xhi,xlo + column-sum partial[blk]
// blocks 128..1151 : lw (flat, hi only)
// blocks 1152..1407: sw1 (flat, hi+lo)
// blocks 1408..1499: u4|u12|u40|u128 -> packed ubh rows {0,4,16,56}
// ---------------------------------------------------------------------------
__global__ __launch_bounds__(256) void conv_kernel(
    const float* __restrict__ x, const float* __restrict__ lw,
    const float* __restrict__ sw1,
    const float* __restrict__ u4, const float* __restrict__ u12,
    const float* __restrict__ u40, const float* __restrict__ u128,
    ushort* __restrict__ xhi, ushort* __restrict__ xlo,
    ushort* __restrict__ lwh, ushort* __restrict__ swh,
    ushort* __restrict__ swl, ushort* __restrict__ ubh,
    float* __restrict__ partial) {
    int blk = blockIdx.x, tid = threadIdx.x;
    if (blk < 128) {
        int c0 = tid << 3;
        float cs0 = 0.f, cs1 = 0.f, cs2 = 0.f, cs3 = 0.f;
        float cs4 = 0.f, cs5 = 0.f, cs6 = 0.f, cs7 = 0.f;
        for (int r = 0; r < 16; ++r) {
            size_t off = (size_t)(blk * 16 + r) * H_ + c0;
            float4 a = *(const float4*)(x + off);
            float4 b = *(const float4*)(x + off + 4);
            cs0 += a.x; cs1 += a.y; cs2 += a.z; cs3 += a.w;
            cs4 += b.x; cs5 += b.y; cs6 += b.z; cs7 += b.w;
            uint4 hi, lo;
            pack_hilo8(a, b, &hi, &lo);
            *(uint4*)(xhi + off) = hi;
            *(uint4*)(xlo + off) = lo;
        }
        float* pr = partial + (size_t)blk * H_ + c0;
        pr[0] = cs0; pr[1] = cs1; pr[2] = cs2; pr[3] = cs3;
        pr[4] = cs4; pr[5] = cs5; pr[6] = cs6; pr[7] = cs7;
    } else if (blk < 1152) {
        size_t base = (size_t)(blk - 128) * 4096 + (size_t)tid * 16;
#pragma unroll
        for (int q = 0; q < 2; ++q) {
            size_t o = base + q * 8;
            float4 a = *(const float4*)(lw + o);
            float4 b = *(const float4*)(lw + o + 4);
            *(uint4*)(lwh + o) = pack_hi8(a, b);
        }
    } else if (blk < 1408) {
        size_t base = (size_t)(blk - 1152) * 4096 + (size_t)tid * 16;
#pragma unroll
        for (int q = 0; q < 2; ++q) {
            size_t o = base + q * 8;
            float4 a = *(const float4*)(sw1 + o);
            float4 b = *(const float4*)(sw1 + o + 4);
            uint4 hi, lo;
            pack_hilo8(a, b, &hi, &lo);
            *(uint4*)(swh + o) = hi;
            *(uint4*)(swl + o) = lo;
        }
    } else {
        const float* src; ushort* dst; int rel;
        if (blk < 1410)      { src = u4;   dst = ubh;            rel = blk - 1408; }
        else if (blk < 1416) { src = u12;  dst = ubh + 4 * H_;   rel = blk - 1410; }
        else if (blk < 1436) { src = u40;  dst = ubh + 16 * H_;  rel = blk - 1416; }
        else                 { src = u128; dst = ubh + 56 * H_;  rel = blk - 1436; }
        size_t base = (size_t)rel * 4096 + (size_t)tid * 16;
#pragma unroll
        for (int q = 0; q < 2; ++q) {
            size_t o = base + q * 8;
            float4 a = *(const float4*)(src + o);
            float4 b = *(const float4*)(src + o + 4);
            *(uint4*)(dst + o) = pack_hi8(a, b);
        }
    }
}

// ---------------------------------------------------------------------------
// pool_final: xp[b][col] = mean over S of x  (from 64 partials per b).
// ---------------------------------------------------------------------------
__global__ __launch_bounds__(256) void pool_final_kernel(
    const float* __restrict__ partial, float* __restrict__ xp) {
    int b = blockIdx.x >> 3, chunk = blockIdx.x & 7;
    int col = (chunk << 8) + threadIdx.x;
    float s = 0.f;
    for (int seg = 0; seg < 64; ++seg)
        s += partial[(size_t)(b * 64 + seg) * H_ + col];
    xp[b * H_ + col] = s * (1.0f / S_);
}

// ---------------------------------------------------------------------------
// decide_dots: 192 blocks, one dot-product output each.
// ---------------------------------------------------------------------------
__global__ __launch_bounds__(256) void decide_dots(
    const float* __restrict__ xp, const float* __restrict__ kpw,
    const float* __restrict__ cw1, float* __restrict__ dots) {
    __shared__ float red[4];
    int o = blockIdx.x, tid = threadIdx.x;
    const float* xr;
    const float* wr;
    if (o < 64) {
        xr = xp + (o >> 5) * H_;
        wr = kpw + (size_t)(o & 31) * H_;
    } else {
        int o2 = o - 64;
        xr = xp + (o2 >> 6) * H_;
        wr = cw1 + (size_t)(o2 & 63) * H_;
    }
    int k0 = tid << 3;
    float4 xa = *(const float4*)(xr + k0);
    float4 xb = *(const float4*)(xr + k0 + 4);
    float4 wa = *(const float4*)(wr + k0);
    float4 wb = *(const float4*)(wr + k0 + 4);
    float s = xa.x * wa.x + xa.y * wa.y + xa.z * wa.z + xa.w * wa.w
            + xb.x * wb.x + xb.y * wb.y + xb.z * wb.z + xb.w * wb.w;
    for (int off = 32; off > 0; off >>= 1) s += __shfl_down(s, off, 64);
    if ((tid & 63) == 0) red[tid >> 6] = s;
    __syncthreads();
    if (tid == 0) dots[o] = red[0] + red[1] + red[2] + red[3];
}

// ---------------------------------------------------------------------------
// decide_final: tiny serial tail (O(4K) FLOP), one block.
// flags: [0]=n_crit (memset) [1]=rank_idx [2]=hit [3]=best
// ---------------------------------------------------------------------------
__global__ __launch_bounds__(64) void decide_final(
    const float* __restrict__ dots, const float* __restrict__ ck,
    const float* __restrict__ cb1, const float* __restrict__ cw2,
    const float* __restrict__ cb2, int* __restrict__ flags) {
    __shared__ float qk_s[64], ce_s[128], sims_s[NC_], sc_s[8];
    __shared__ float qn_s;
    int tid = threadIdx.x;
    if (tid < 64) qk_s[tid] = dots[tid];
    if (tid < 64) {
        ce_s[tid]      = fmaxf(dots[64 + tid] + cb1[tid & 63], 0.f);
        ce_s[tid + 64] = fmaxf(dots[128 + tid] + cb1[tid & 63], 0.f);
    }
    __syncthreads();
    if (tid == 0) {
        for (int b = 0; b < B_; ++b) {
            float nn = 0.f;
            for (int d = 0; d < KD_; ++d) { float v = qk_s[b * KD_ + d]; nn += v * v; }
            float den = fmaxf(sqrtf(nn), 1e-8f);
            for (int d = 0; d < KD_; ++d) qk_s[b * KD_ + d] /= den;
        }
        float qn = 0.f;
        for (int i = 0; i < B_ * KD_; ++i) qn += qk_s[i] * qk_s[i];
        qn_s = fmaxf(sqrtf(qn), 1e-8f);
    }
    __syncthreads();
    if (tid < NC_) {
        float dot = 0.f, nn = 0.f;
        for (int i = 0; i < B_ * KD_; ++i) {
            float c = ck[tid * (B_ * KD_) + i];
            dot += c * qk_s[i]; nn += c * c;
        }
        sims_s[tid] = dot / (fmaxf(sqrtf(nn), 1e-8f) * qn_s);
    }
    if (tid >= 32 && tid < 40) {
        int p = tid - 32, b = p >> 2, o = p & 3;
        float v = cb2[o];
        for (int j = 0; j < 64; ++j) v += ce_s[b * 64 + j] * cw2[o * 64 + j];
        sc_s[p] = v;
    }
    __syncthreads();
    if (tid == 0) {
        float bestv = -1e30f; int best = 0;
        for (int n = 0; n < NC_; ++n)
            if (sims_s[n] > bestv) { bestv = sims_s[n]; best = n; }
        flags[2] = (bestv >= 0.95f) ? 1 : 0;
        flags[3] = best;
        float bs = -1e30f; int bi = 0;
        for (int p = 0; p < 8; ++p)
            if (sc_s[p] > bs) { bs = sc_s[p]; bi = p; }
        flags[1] = bi & 3;
    }
}

// ---------------------------------------------------------------------------
// big_gemm: fused scorer (split-bf16) + all-rank projections.
// m97 staging (global_load_lds w16) + 2-phase double-buffer: STAGE(next)
// issued BEFORE compute(cur); ONE __syncthreads per K-step (implicit
// vmcnt(0)+lgkmcnt(0) drain covers both hazards). kz=4 -> 384 blocks,
// 64KB LDS -> 2 blocks/CU co-resident for cross-block latency hiding.
//   y<4 : Hp[kz] tiles = xh·swh + xh·swl + xl·swh   (3 MFMA)
//   y>=4: Pp[kz] tiles = xh·ubh                      (1 MFMA; ubh 256 rows)
// ---------------------------------------------------------------------------
__global__ __launch_bounds__(256) void big_gemm(
    const ushort* __restrict__ xhi, const ushort* __restrict__ xlo,
    const ushort* __restrict__ swh, const ushort* __restrict__ swl,
    const ushort* __restrict__ ubh,
    float* __restrict__ Hp, float* __restrict__ Pp) {
    __shared__ ushort Ah[2][128][32], Al[2][128][32], Bh[2][128][32], Bl[2][128][32];
    int m0 = blockIdx.x << 7;
    int ny = blockIdx.y;
    int kz = blockIdx.z;
    bool split = ny < 4;
    int tid = threadIdx.x;
    int lr = tid >> 2;              // staging row 0..63 (and +64)
    int lc = (tid & 3) << 3;        // staging col in ushorts: 0/8/16/24

    const ushort* a0p = xhi + (size_t)(m0 + lr) * H_ + lc;
    const ushort* a1p = a0p + (size_t)64 * H_;
    const ushort* l0p = xlo + (size_t)(m0 + lr) * H_ + lc;
    const ushort* l1p = l0p + (size_t)64 * H_;
    const ushort* b0p; const ushort* b1p;
    const ushort* c0p = l0p; const ushort* c1p = l1p;
    if (split) {
        b0p = swh + (size_t)(ny * 128 + lr) * H_ + lc;
        b1p = b0p + (size_t)64 * H_;
        c0p = swl + (size_t)(ny * 128 + lr) * H_ + lc;
        c1p = c0p + (size_t)64 * H_;
    } else {
        b0p = ubh + (size_t)((ny - 4) * 128 + lr) * H_ + lc;  // rows <256, padded
        b1p = b0p + (size_t)64 * H_;
    }

    int lane = tid & 63, w = tid >> 6;
    int wm = (w >> 1) << 6, wn = (w & 1) << 6;
    int fr = lane & 15, kb = (lane >> 4) << 3;

    f32x4 zero4 = {0.f, 0.f, 0.f, 0.f};
    f32x4 acc[4][4];
#pragma unroll
    for (int i = 0; i < 4; ++i)
#pragma unroll
        for (int j = 0; j < 4; ++j) acc[i][j] = zero4;

    int kbeg = kz << 9;             // 512 K per kz-slice, 16 K-steps

#define STAGE_BG(bb, k0)                                                  \
    do {                                                                  \
        gld16(a0p + (k0), &Ah[bb][lr][lc]);                               \
        gld16(a1p + (k0), &Ah[bb][lr + 64][lc]);                          \
        gld16(b0p + (k0), &Bh[bb][lr][lc]);                               \
        gld16(b1p + (k0), &Bh[bb][lr + 64][lc]);                          \
        if (split) {                                                      \
            gld16(l0p + (k0), &Al[bb][lr][lc]);                           \
            gld16(l1p + (k0), &Al[bb][lr + 64][lc]);                      \
            gld16(c0p + (k0), &Bl[bb][lr][lc]);                           \
            gld16(c1p + (k0), &Bl[bb][lr + 64][lc]);                      \
        }                                                                 \
    } while (0)

    STAGE_BG(0, kbeg);
    __syncthreads();                // buf0 resident
    int cur = 0;
    for (int kt = 0; kt < 16; ++kt) {
        if (kt + 1 < 16) STAGE_BG(cur ^ 1, kbeg + ((kt + 1) << 5));
        bf16x8 ah[4], bh4[4], al4[4], bl4[4];
#pragma unroll
        for (int mt = 0; mt < 4; ++mt)
            ah[mt] = *(const bf16x8*)&Ah[cur][wm + (mt << 4) + fr][kb];
#pragma unroll
        for (int nt = 0; nt < 4; ++nt)
            bh4[nt] = *(const bf16x8*)&Bh[cur][wn + (nt << 4) + fr][kb];
        if (split) {
#pragma unroll
            for (int mt = 0; mt < 4; ++mt)
                al4[mt] = *(const bf16x8*)&Al[cur][wm + (mt << 4) + fr][kb];
#pragma unroll
            for (int nt = 0; nt < 4; ++nt)
                bl4[nt] = *(const bf16x8*)&Bl[cur][wn + (nt << 4) + fr][kb];
        }
#pragma unroll
        for (int mt = 0; mt < 4; ++mt)
#pragma unroll
            for (int nt = 0; nt < 4; ++nt) {
                acc[mt][nt] = __builtin_amdgcn_mfma_f32_16x16x32_bf16(
                    ah[mt], bh4[nt], acc[mt][nt], 0, 0, 0);
                if (split) {
                    acc[mt][nt] = __builtin_amdgcn_mfma_f32_16x16x32_bf16(
                        ah[mt], bl4[nt], acc[mt][nt], 0, 0, 0);
                    acc[mt][nt] = __builtin_amdgcn_mfma_f32_16x16x32_bf16(
                        al4[mt], bh4[nt], acc[mt][nt], 0, 0, 0);
                }
            }
        __syncthreads();            // next buf resident + all reads of cur done
        cur ^= 1;
    }
#undef STAGE_BG

    int orr = (lane >> 4) << 2;
    if (split) {
        float* dst = Hp + (size_t)kz * M_ * F_;
#pragma unroll
        for (int mt = 0; mt < 4; ++mt)
#pragma unroll
            for (int r = 0; r < 4; ++r) {
                int m = m0 + wm + (mt << 4) + orr + r;
                float* cr = dst + (size_t)m * F_ + (ny << 7) + wn;
#pragma unroll
                for (int nt = 0; nt < 4; ++nt)
                    cr[(nt << 4) + fr] = acc[mt][nt][r];
            }
    } else {
        float* dst = Pp + (size_t)kz * M_ * LDP;
        int nb0 = (ny - 4) << 7;
#pragma unroll
        for (int mt = 0; mt < 4; ++mt)
#pragma unroll
            for (int r = 0; r < 4; ++r) {
                int m = m0 + wm + (mt << 4) + orr + r;
                float* cr = dst + (size_t)m * LDP;
#pragma unroll
                for (int nt = 0; nt < 4; ++nt) {
                    int c = nb0 + wn + (nt << 4) + fr;
                    if (c < NPROJ) cr[c] = acc[mt][nt][r];
                }
            }
    }
}

// ---------------------------------------------------------------------------
// route_kernel: token routing from Hp partials (KZ_=4). 512 blocks.
// ---------------------------------------------------------------------------
__global__ __launch_bounds__(256) void route_kernel(
    const float* __restrict__ Hp, const float* __restrict__ sb1,
    const float* __restrict__ sw2, const float* __restrict__ sb2,
    const float* __restrict__ pos,
    int* __restrict__ flags, int* __restrict__ route, int* __restrict__ clist) {
    int tid = threadIdx.x;
    int m = (blockIdx.x << 2) + (tid >> 6);
    int lane = tid & 63;
    const float* h0 = Hp + (size_t)m * F_;
    const float* h1 = h0 + (size_t)M_ * F_;
    const float* h2 = h1 + (size_t)M_ * F_;
    const float* h3 = h2 + (size_t)M_ * F_;
    float s = 0.f;
    for (int f = lane; f < F_; f += 64)
        s += fmaxf(h0[f] + h1[f] + h2[f] + h3[f] + sb1[f], 0.f) * sw2[f];
    for (int off = 32; off > 0; off >>= 1) s += __shfl_down(s, off, 64);
    if (lane == 0) {
        float content = s + sb2[0];
        int si = m & (S_ - 1);
        float imp = 1.0f / (1.0f + expf(-(content + 0.1f * pos[si])));
        if (si == 0 || si == S_ - 1) imp *= 2.0f;
        int rt = (imp > 0.8f) ? 0 : ((imp < 0.3f) ? 1 : 2);
        route[m] = rt;
        if (rt == 0) {
            int idx = atomicAdd(&flags[0], 1);
            clist[idx] = m;
        }
    }
}

// ---------------------------------------------------------------------------
// crit_gemm: gathered-row bf16 MFMA GEMM, m97 staging + 2-phase dbuf,
// out[row] = x[row]@lw^T + lb.
// ---------------------------------------------------------------------------
__global__ __launch_bounds__(256) void crit_gemm(
    const ushort* __restrict__ xhi, const ushort* __restrict__ lwh,
    const float* __restrict__ lb, const int* __restrict__ clist,
    const int* __restrict__ flags, float* __restrict__ out) {
    __shared__ ushort Ah[2][128][32], Bh[2][128][32];
    int M = flags[0];
    int m0 = blockIdx.x << 7;
    if (m0 >= M) return;
    int n0 = blockIdx.y << 7;
    int tid = threadIdx.x;
    int lr = tid >> 2, lc = (tid & 3) << 3;

    int gm0 = m0 + lr, gm1 = m0 + lr + 64;
    int ar0 = clist[gm0 < M ? gm0 : (M - 1)];
    int ar1 = clist[gm1 < M ? gm1 : (M - 1)];
    const ushort* a0p = xhi + (size_t)ar0 * H_ + lc;
    const ushort* a1p = xhi + (size_t)ar1 * H_ + lc;
    const ushort* b0p = lwh + (size_t)(n0 + lr) * H_ + lc;
    const ushort* b1p = b0p + (size_t)64 * H_;

    int lane = tid & 63, w = tid >> 6;
    int wm = (w >> 1) << 6, wn = (w & 1) << 6;
    int fr = lane & 15, kb = (lane >> 4) << 3;

    f32x4 zero4 = {0.f, 0.f, 0.f, 0.f};
    f32x4 acc[4][4];
#pragma unroll
    for (int i = 0; i < 4; ++i)
#pragma unroll
        for (int j = 0; j < 4; ++j) acc[i][j] = zero4;

#define STAGE_CG(bb, k0)                                                  \
    do {                                                                  \
        gld16(a0p + (k0), &Ah[bb][lr][lc]);                               \
        gld16(a1p + (k0), &Ah[bb][lr + 64][lc]);                          \
        gld16(b0p + (k0), &Bh[bb][lr][lc]);                               \
        gld16(b1p + (k0), &Bh[bb][lr + 64][lc]);                          \
    } while (0)

    STAGE_CG(0, 0);
    __syncthreads();
    int cur = 0;
    for (int kt = 0; kt < 64; ++kt) {
        if (kt + 1 < 64) STAGE_CG(cur ^ 1, (kt + 1) << 5);
        bf16x8 af[4], bf4[4];
#pragma unroll
        for (int mt = 0; mt < 4; ++mt)
            af[mt] = *(const bf16x8*)&Ah[cur][wm + (mt << 4) + fr][kb];
#pragma unroll
        for (int nt = 0; nt < 4; ++nt)
            bf4[nt] = *(const bf16x8*)&Bh[cur][wn + (nt << 4) + fr][kb];
#pragma unroll
        for (int mt = 0; mt < 4; ++mt)
#pragma unroll
            for (int nt = 0; nt < 4; ++nt)
                acc[mt][nt] = __builtin_amdgcn_mfma_f32_16x16x32_bf16(
                    af[mt], bf4[nt], acc[mt][nt], 0, 0, 0);
        __syncthreads();
        cur ^= 1;
    }
#undef STAGE_CG

    int orr = (lane >> 4) << 2;
#pragma unroll
    for (int mt = 0; mt < 4; ++mt)
#pragma unroll
        for (int r = 0; r < 4; ++r) {
            int m = m0 + wm + (mt << 4) + orr + r;
            if (m < M) {
                float* cr = out + (size_t)clist[m] * H_;
#pragma unroll
                for (int nt = 0; nt < 4; ++nt) {
                    int c = n0 + wn + (nt << 4) + fr;
                    cr[c] = acc[mt][nt][r] + lb[c];
                }
            }
        }
}

// ---------------------------------------------------------------------------
// stage2: merged simple+normal epilogue, column-split for occupancy.
// grid = 128 m-chunks x 16 col-chunks = 2048 blocks (8/CU).
// route==1: out = x + (hit ? cache_delta[best] : t4 @ v4^T)
// route==2: out = x + tr @ v_rank^T      (Pp has KZ_=4 partials)
// ---------------------------------------------------------------------------
__global__ __launch_bounds__(256) void stage2_kernel(
    const float* __restrict__ x, const float* __restrict__ Pp,
    const float* __restrict__ v4, const float* __restrict__ v12,
    const float* __restrict__ v40, const float* __restrict__ v128,
    const float* __restrict__ cd, const int* __restrict__ flags,
    const int* __restrict__ route, float* __restrict__ out) {
    __shared__ float TsR[16][132];
    __shared__ float Ts4[16][4];
    __shared__ int rt_s[16];
    int tid = threadIdx.x;
    int m0 = (blockIdx.x >> 4) << 4;       // token chunk
    int c0 = (blockIdx.x & 15) << 7;       // column chunk (128 cols)

    if (tid < 16) rt_s[tid] = route[m0 + tid];
    int r = flags[1];
    const float* V = (r == 0) ? v4 : (r == 1) ? v12 : (r == 2) ? v40 : v128;
    int Kr  = (r == 0) ? 4 : (r == 1) ? 12 : (r == 2) ? 40 : 128;
    int off = (r == 0) ? 0 : (r == 1) ? 4  : (r == 2) ? 16 : 56;
    int hit = flags[2], best = flags[3];

    const float* Pp1 = Pp + (size_t)M_ * LDP;
    const float* Pp2 = Pp1 + (size_t)M_ * LDP;
    const float* Pp3 = Pp2 + (size_t)M_ * LDP;
    for (int idx = tid; idx < 16 * Kr; idx += 256) {
        int i = idx / Kr, j = idx - i * Kr;
        size_t o = (size_t)(m0 + i) * LDP + off + j;
        TsR[i][j] = Pp[o] + Pp1[o] + Pp2[o] + Pp3[o];
    }
    if (tid < 64) {
        int i = tid >> 2, j = tid & 3;
        size_t o = (size_t)(m0 + i) * LDP + j;
        Ts4[i][j] = Pp[o] + Pp1[o] + Pp2[o] + Pp3[o];
    }
    __syncthreads();
    bool any1 = false, any2 = false;
#pragma unroll
    for (int i = 0; i < 16; ++i) { any1 |= (rt_s[i] == 1); any2 |= (rt_s[i] == 2); }
    if (!any1 && !any2) return;
    bool need4 = any1 && !hit;

    int c = c0 + (tid & 127);
    int i0 = (tid >> 7) << 3;              // 0 or 8: token half per wave-pair

    float aR[8];
#pragma unroll
    for (int i = 0; i < 8; ++i) aR[i] = 0.f;
    if (any2) {
        const float* vrow = V + (size_t)c * Kr;
        for (int j = 0; j < Kr; j += 4) {
            const float4 vv = *(const float4*)(vrow + j);
#pragma unroll
            for (int i = 0; i < 8; ++i) {
                const float4 tv = *(const float4*)&TsR[i0 + i][j];
                aR[i] += tv.x * vv.x + tv.y * vv.y + tv.z * vv.z + tv.w * vv.w;
            }
        }
    }
    float a4[8];
    if (need4) {
        const float4 vv = *(const float4*)(v4 + (size_t)c * 4);
#pragma unroll
        for (int i = 0; i < 8; ++i) {
            const float4 tv = *(const float4*)&Ts4[i0 + i][0];
            a4[i] = tv.x * vv.x + tv.y * vv.y + tv.z * vv.z + tv.w * vv.w;
        }
    }
#pragma unroll
    for (int i = 0; i < 8; ++i) {
        int rt = rt_s[i0 + i];
        if (rt == 0) continue;
        size_t o = (size_t)(m0 + i0 + i) * H_ + c;
        float upd;
        if (rt == 1)
            upd = hit ? cd[(size_t)best * (size_t)(M_ * H_) + o] : a4[i];
        else
            upd = aR[i];
        out[o] = x[o] + upd;
    }
}

// ---------------------------------------------------------------------------
extern "C" void kernel_launch(void* const* d_in, const int* in_sizes, int n_in,
                              void* d_out, int out_size, void* d_ws, size_t ws_size,
                              hipStream_t stream) {
    const float* x    = (const float*)d_in[0];
    const float* sw1  = (const float*)d_in[1];
    const float* sb1  = (const float*)d_in[2];
    const float* sw2  = (const float*)d_in[3];
    const float* sb2  = (const float*)d_in[4];
    const float* pos  = (const float*)d_in[5];
    const float* kpw  = (const float*)d_in[6];
    const float* ck   = (const float*)d_in[7];
    const float* cd   = (const float*)d_in[8];
    const float* cw1  = (const float*)d_in[9];
    const float* cb1  = (const float*)d_in[10];
    const float* cw2  = (const float*)d_in[11];
    const float* cb2  = (const float*)d_in[12];
    const float* u4   = (const float*)d_in[13];
    const float* v4   = (const float*)d_in[14];
    const float* u12  = (const float*)d_in[15];
    const float* v12  = (const float*)d_in[16];
    const float* u40  = (const float*)d_in[17];
    const float* v40  = (const float*)d_in[18];
    const float* u128 = (const float*)d_in[19];
    const float* v128 = (const float*)d_in[20];
    const float* lw   = (const float*)d_in[21];
    const float* lb   = (const float*)d_in[22];
    float* out = (float*)d_out;

    // ---- workspace layout (~54 MB of the 1 GiB ws) ----
    ushort* xhi = (ushort*)d_ws;                       // [M,H]
    ushort* xlo = xhi + (size_t)M_ * H_;               // [M,H]
    ushort* lwh = xlo + (size_t)M_ * H_;               // [H,H]
    ushort* swh = lwh + (size_t)H_ * H_;               // [F,H]
    ushort* swl = swh + (size_t)F_ * H_;               // [F,H]
    ushort* ubh = swl + (size_t)F_ * H_;               // [256,H] (184 valid)
    float* fbase   = (float*)(ubh + (size_t)256 * H_);
    float* xp      = fbase;                            // [2,H]
    float* partial = xp + 2 * H_;                      // [128,H]
    float* Pp      = partial + 128 * H_;               // [KZ_,M,LDP]
    float* Hp      = Pp + (size_t)KZ_ * M_ * LDP;      // [KZ_,M,F]
    float* dots    = Hp + (size_t)KZ_ * M_ * F_;       // [192]
    int*   flags   = (int*)(dots + 256);
    int*   route   = flags + 8;                        // [M]
    int*   clist   = route + M_;                       // [M]

    hipMemsetAsync(flags, 0, sizeof(int), stream);   // n_crit = 0

    conv_kernel<<<1500, 256, 0, stream>>>(x, lw, sw1, u4, u12, u40, u128,
                                          xhi, xlo, lwh, swh, swl, ubh, partial);
    pool_final_kernel<<<16, 256, 0, stream>>>(partial, xp);
    decide_dots<<<192, 256, 0, stream>>>(xp, kpw, cw1, dots);
    decide_final<<<1, 64, 0, stream>>>(dots, ck, cb1, cw2, cb2, flags);
    big_gemm<<<dim3(16, 6, KZ_), 256, 0, stream>>>(xhi, xlo, swh, swl, ubh, Hp, Pp);
    route_kernel<<<512, 256, 0, stream>>>(Hp, sb1, sw2, sb2, pos,
                                          flags, route, clist);
    crit_gemm<<<dim3(16, 16), 256, 0, stream>>>(xhi, lwh, lb, clist, flags, out);
    stage2_kernel<<<2048, 256, 0, stream>>>(x, Pp, v4, v12, v40, v128,
                                            cd, flags, route, out);
}

// Round 4
// 479.581 us; speedup vs baseline: 1.3489x; 1.0823x over previous
//
#include <hip/hip_runtime.h>
#include <math.h>

#define B_  2
#define S_  1024
#define H_  2048
#define F_  512          // H/4
#define KD_ 32
#define NC_ 16
#define M_  2048         // B*S tokens
#define NPROJ 184        // 4+12+40+128 packed u-rows
#define LDP 192          // proj row stride
#define KZ_ 4            // K-split factor for big_gemm

typedef __attribute__((ext_vector_type(8))) short bf16x8;
typedef __attribute__((ext_vector_type(4))) float f32x4;

typedef __attribute__((address_space(1))) const void gvoid_t;
typedef __attribute__((address_space(3))) void lvoid_t;

// async global -> LDS, 16B per lane. LDS dest must be wave-uniform base + lane*16.
__device__ __forceinline__ void gld16(const void* g, void* l) {
    __builtin_amdgcn_global_load_lds((gvoid_t*)g, (lvoid_t*)l, 16, 0, 0);
}

__device__ __forceinline__ ushort f2bf(float f) {
    unsigned u = __float_as_uint(f);
    u += 0x7FFFu + ((u >> 16) & 1u);   // RNE
    return (ushort)(u >> 16);
}
__device__ __forceinline__ float bf2f(ushort h) {
    return __uint_as_float(((unsigned)h) << 16);
}
__device__ __forceinline__ uint4 pack_hi8(float4 a, float4 b) {
    uint4 r;
    r.x = (unsigned)f2bf(a.x) | ((unsigned)f2bf(a.y) << 16);
    r.y = (unsigned)f2bf(a.z) | ((unsigned)f2bf(a.w) << 16);
    r.z = (unsigned)f2bf(b.x) | ((unsigned)f2bf(b.y) << 16);
    r.w = (unsigned)f2bf(b.z) | ((unsigned)f2bf(b.w) << 16);
    return r;
}
__device__ __forceinline__ void pack_hilo8(float4 a, float4 b, uint4* hi, uint4* lo) {
    float v[8] = {a.x, a.y, a.z, a.w, b.x, b.y, b.z, b.w};
    unsigned h[8], l[8];
#pragma unroll
    for (int i = 0; i < 8; ++i) {
        ushort hh = f2bf(v[i]);
        h[i] = hh;
        l[i] = f2bf(v[i] - bf2f(hh));
    }
    *hi = make_uint4(h[0] | (h[1] << 16), h[2] | (h[3] << 16),
                     h[4] | (h[5] << 16), h[6] | (h[7] << 16));
    *lo = make_uint4(l[0] | (l[1] << 16), l[2] | (l[3] << 16),
                     l[4] | (l[5] << 16), l[6] | (l[7] << 16));
}

// ---------------------------------------------------------------------------
// conv_kernel: bf16 conversions + pool partials, one pass.
// ---------------------------------------------------------------------------
__global__ __launch_bounds__(256) void conv_kernel(
    const float* __restrict__ x, const float* __restrict__ lw,
    const float* __restrict__ sw1,
    const float* __restrict__ u4, const float* __restrict__ u12,
    const float* __restrict__ u40, const float* __restrict__ u128,
    ushort* __restrict__ xhi, ushort* __restrict__ xlo,
    ushort* __restrict__ lwh, ushort* __restrict__ swh,
    ushort* __restrict__ swl, ushort* __restrict__ ubh,
    float* __restrict__ partial) {
    int blk = blockIdx.x, tid = threadIdx.x;
    if (blk < 128) {
        int c0 = tid << 3;
        float cs0 = 0.f, cs1 = 0.f, cs2 = 0.f, cs3 = 0.f;
        float cs4 = 0.f, cs5 = 0.f, cs6 = 0.f, cs7 = 0.f;
        for (int r = 0; r < 16; ++r) {
            size_t off = (size_t)(blk * 16 + r) * H_ + c0;
            float4 a = *(const float4*)(x + off);
            float4 b = *(const float4*)(x + off + 4);
            cs0 += a.x; cs1 += a.y; cs2 += a.z; cs3 += a.w;
            cs4 += b.x; cs5 += b.y; cs6 += b.z; cs7 += b.w;
            uint4 hi, lo;
            pack_hilo8(a, b, &hi, &lo);
            *(uint4*)(xhi + off) = hi;
            *(uint4*)(xlo + off) = lo;
        }
        float* pr = partial + (size_t)blk * H_ + c0;
        pr[0] = cs0; pr[1] = cs1; pr[2] = cs2; pr[3] = cs3;
        pr[4] = cs4; pr[5] = cs5; pr[6] = cs6; pr[7] = cs7;
    } else if (blk < 1152) {
        size_t base = (size_t)(blk - 128) * 4096 + (size_t)tid * 16;
#pragma unroll
        for (int q = 0; q < 2; ++q) {
            size_t o = base + q * 8;
            float4 a = *(const float4*)(lw + o);
            float4 b = *(const float4*)(lw + o + 4);
            *(uint4*)(lwh + o) = pack_hi8(a, b);
        }
    } else if (blk < 1408) {
        size_t base = (size_t)(blk - 1152) * 4096 + (size_t)tid * 16;
#pragma unroll
        for (int q = 0; q < 2; ++q) {
            size_t o = base + q * 8;
            float4 a = *(const float4*)(sw1 + o);
            float4 b = *(const float4*)(sw1 + o + 4);
            uint4 hi, lo;
            pack_hilo8(a, b, &hi, &lo);
            *(uint4*)(swh + o) = hi;
            *(uint4*)(swl + o) = lo;
        }
    } else {
        const float* src; ushort* dst; int rel;
        if (blk < 1410)      { src = u4;   dst = ubh;            rel = blk - 1408; }
        else if (blk < 1416) { src = u12;  dst = ubh + 4 * H_;   rel = blk - 1410; }
        else if (blk < 1436) { src = u40;  dst = ubh + 16 * H_;  rel = blk - 1416; }
        else                 { src = u128; dst = ubh + 56 * H_;  rel = blk - 1436; }
        size_t base = (size_t)rel * 4096 + (size_t)tid * 16;
#pragma unroll
        for (int q = 0; q < 2; ++q) {
            size_t o = base + q * 8;
            float4 a = *(const float4*)(src + o);
            float4 b = *(const float4*)(src + o + 4);
            *(uint4*)(dst + o) = pack_hi8(a, b);
        }
    }
}

// ---------------------------------------------------------------------------
// pooldots: fused pool_final + decide_dots. 192 blocks, each computes its
// xp slice in-register (bit-identical order) then one dot-product output.
// ---------------------------------------------------------------------------
__global__ __launch_bounds__(256) void pooldots_kernel(
    const float* __restrict__ partial, const float* __restrict__ kpw,
    const float* __restrict__ cw1, float* __restrict__ dots) {
    __shared__ float red[4];
    int o = blockIdx.x, tid = threadIdx.x;
    int b; const float* wr;
    if (o < 64) {
        b = o >> 5;
        wr = kpw + (size_t)(o & 31) * H_;
    } else {
        int o2 = o - 64;
        b = o2 >> 6;
        wr = cw1 + (size_t)(o2 & 63) * H_;
    }
    int k0 = tid << 3;
    float xs0 = 0.f, xs1 = 0.f, xs2 = 0.f, xs3 = 0.f;
    float xs4 = 0.f, xs5 = 0.f, xs6 = 0.f, xs7 = 0.f;
    const float* pb = partial + (size_t)b * 64 * H_ + k0;
    for (int seg = 0; seg < 64; ++seg) {
        float4 p0 = *(const float4*)(pb + (size_t)seg * H_);
        float4 p1 = *(const float4*)(pb + (size_t)seg * H_ + 4);
        xs0 += p0.x; xs1 += p0.y; xs2 += p0.z; xs3 += p0.w;
        xs4 += p1.x; xs5 += p1.y; xs6 += p1.z; xs7 += p1.w;
    }
    const float inv = 1.0f / S_;
    float4 wa = *(const float4*)(wr + k0);
    float4 wb = *(const float4*)(wr + k0 + 4);
    float s = (xs0 * inv) * wa.x + (xs1 * inv) * wa.y
            + (xs2 * inv) * wa.z + (xs3 * inv) * wa.w
            + (xs4 * inv) * wb.x + (xs5 * inv) * wb.y
            + (xs6 * inv) * wb.z + (xs7 * inv) * wb.w;
    for (int off = 32; off > 0; off >>= 1) s += __shfl_down(s, off, 64);
    if ((tid & 63) == 0) red[tid >> 6] = s;
    __syncthreads();
    if (tid == 0) dots[o] = red[0] + red[1] + red[2] + red[3];
}

// ---------------------------------------------------------------------------
// big_gemm: fused scorer (split-bf16) + all-rank projections.
// m97 staging + 2-phase dbuf + T2 bank-conflict fix: LDS dest stays linear,
// global SOURCE column pre-swizzled (lcs = lc ^ s(lr)), reads XOR the same
// s(row) -> 2 lanes/bank (free) instead of 8-way on ds_read_b128.
// ---------------------------------------------------------------------------
__global__ __launch_bounds__(256) void big_gemm(
    const ushort* __restrict__ xhi, const ushort* __restrict__ xlo,
    const ushort* __restrict__ swh, const ushort* __restrict__ swl,
    const ushort* __restrict__ ubh,
    float* __restrict__ Hp, float* __restrict__ Pp) {
    __shared__ ushort Ah[2][128][32], Al[2][128][32], Bh[2][128][32], Bl[2][128][32];
    int m0 = blockIdx.x << 7;
    int ny = blockIdx.y;
    int kz = blockIdx.z;
    bool split = ny < 4;
    int tid = threadIdx.x;
    int lr = tid >> 2;              // staging row 0..63 (and +64)
    int lc = (tid & 3) << 3;        // LDS col (ushorts): 0/8/16/24 (linear dest)
    int lcs = lc ^ (((lr >> 1) & 3) << 3);   // pre-swizzled SOURCE col

    const ushort* a0p = xhi + (size_t)(m0 + lr) * H_ + lcs;
    const ushort* a1p = a0p + (size_t)64 * H_;
    const ushort* l0p = xlo + (size_t)(m0 + lr) * H_ + lcs;
    const ushort* l1p = l0p + (size_t)64 * H_;
    const ushort* b0p; const ushort* b1p;
    const ushort* c0p = l0p; const ushort* c1p = l1p;
    if (split) {
        b0p = swh + (size_t)(ny * 128 + lr) * H_ + lcs;
        b1p = b0p + (size_t)64 * H_;
        c0p = swl + (size_t)(ny * 128 + lr) * H_ + lcs;
        c1p = c0p + (size_t)64 * H_;
    } else {
        b0p = ubh + (size_t)((ny - 4) * 128 + lr) * H_ + lcs;  // rows <256, padded
        b1p = b0p + (size_t)64 * H_;
    }

    int lane = tid & 63, w = tid >> 6;
    int wm = (w >> 1) << 6, wn = (w & 1) << 6;
    int fr = lane & 15;
    int kb = ((lane >> 4) << 3) ^ (((fr >> 1) & 3) << 3);  // swizzled read col

    f32x4 zero4 = {0.f, 0.f, 0.f, 0.f};
    f32x4 acc[4][4];
#pragma unroll
    for (int i = 0; i < 4; ++i)
#pragma unroll
        for (int j = 0; j < 4; ++j) acc[i][j] = zero4;

    int kbeg = kz << 9;             // 512 K per kz-slice, 16 K-steps

#define STAGE_BG(bb, k0)                                                  \
    do {                                                                  \
        gld16(a0p + (k0), &Ah[bb][lr][lc]);                               \
        gld16(a1p + (k0), &Ah[bb][lr + 64][lc]);                          \
        gld16(b0p + (k0), &Bh[bb][lr][lc]);                               \
        gld16(b1p + (k0), &Bh[bb][lr + 64][lc]);                          \
        if (split) {                                                      \
            gld16(l0p + (k0), &Al[bb][lr][lc]);                           \
            gld16(l1p + (k0), &Al[bb][lr + 64][lc]);                      \
            gld16(c0p + (k0), &Bl[bb][lr][lc]);                           \
            gld16(c1p + (k0), &Bl[bb][lr + 64][lc]);                      \
        }                                                                 \
    } while (0)

    STAGE_BG(0, kbeg);
    __syncthreads();                // buf0 resident
    int cur = 0;
    for (int kt = 0; kt < 16; ++kt) {
        if (kt + 1 < 16) STAGE_BG(cur ^ 1, kbeg + ((kt + 1) << 5));
        bf16x8 ah[4], bh4[4], al4[4], bl4[4];
#pragma unroll
        for (int mt = 0; mt < 4; ++mt)
            ah[mt] = *(const bf16x8*)&Ah[cur][wm + (mt << 4) + fr][kb];
#pragma unroll
        for (int nt = 0; nt < 4; ++nt)
            bh4[nt] = *(const bf16x8*)&Bh[cur][wn + (nt << 4) + fr][kb];
        if (split) {
#pragma unroll
            for (int mt = 0; mt < 4; ++mt)
                al4[mt] = *(const bf16x8*)&Al[cur][wm + (mt << 4) + fr][kb];
#pragma unroll
            for (int nt = 0; nt < 4; ++nt)
                bl4[nt] = *(const bf16x8*)&Bl[cur][wn + (nt << 4) + fr][kb];
        }
#pragma unroll
        for (int mt = 0; mt < 4; ++mt)
#pragma unroll
            for (int nt = 0; nt < 4; ++nt) {
                acc[mt][nt] = __builtin_amdgcn_mfma_f32_16x16x32_bf16(
                    ah[mt], bh4[nt], acc[mt][nt], 0, 0, 0);
                if (split) {
                    acc[mt][nt] = __builtin_amdgcn_mfma_f32_16x16x32_bf16(
                        ah[mt], bl4[nt], acc[mt][nt], 0, 0, 0);
                    acc[mt][nt] = __builtin_amdgcn_mfma_f32_16x16x32_bf16(
                        al4[mt], bh4[nt], acc[mt][nt], 0, 0, 0);
                }
            }
        __syncthreads();            // next buf resident + all reads of cur done
        cur ^= 1;
    }
#undef STAGE_BG

    int orr = (lane >> 4) << 2;
    if (split) {
        float* dst = Hp + (size_t)kz * M_ * F_;
#pragma unroll
        for (int mt = 0; mt < 4; ++mt)
#pragma unroll
            for (int r = 0; r < 4; ++r) {
                int m = m0 + wm + (mt << 4) + orr + r;
                float* cr = dst + (size_t)m * F_ + (ny << 7) + wn;
#pragma unroll
                for (int nt = 0; nt < 4; ++nt)
                    cr[(nt << 4) + fr] = acc[mt][nt][r];
            }
    } else {
        float* dst = Pp + (size_t)kz * M_ * LDP;
        int nb0 = (ny - 4) << 7;
#pragma unroll
        for (int mt = 0; mt < 4; ++mt)
#pragma unroll
            for (int r = 0; r < 4; ++r) {
                int m = m0 + wm + (mt << 4) + orr + r;
                float* cr = dst + (size_t)m * LDP;
#pragma unroll
                for (int nt = 0; nt < 4; ++nt) {
                    int c = nb0 + wn + (nt << 4) + fr;
                    if (c < NPROJ) cr[c] = acc[mt][nt][r];
                }
            }
    }
}

// ---------------------------------------------------------------------------
// routefinal: blocks 0..511 = token routing from Hp partials (KZ_=4);
// block 512 = decide_final tail (sims/rank decision into flags[1..3]).
// ---------------------------------------------------------------------------
__global__ __launch_bounds__(256) void routefinal_kernel(
    const float* __restrict__ Hp, const float* __restrict__ sb1,
    const float* __restrict__ sw2, const float* __restrict__ sb2,
    const float* __restrict__ pos,
    const float* __restrict__ dots, const float* __restrict__ ck,
    const float* __restrict__ cb1, const float* __restrict__ cw2,
    const float* __restrict__ cb2,
    int* __restrict__ flags, int* __restrict__ route, int* __restrict__ clist) {
    int tid = threadIdx.x;
    if (blockIdx.x < 512) {
        int m = ((int)blockIdx.x << 2) + (tid >> 6);
        int lane = tid & 63;
        const float* h0 = Hp + (size_t)m * F_;
        const float* h1 = h0 + (size_t)M_ * F_;
        const float* h2 = h1 + (size_t)M_ * F_;
        const float* h3 = h2 + (size_t)M_ * F_;
        float s = 0.f;
        for (int f = lane; f < F_; f += 64)
            s += fmaxf(h0[f] + h1[f] + h2[f] + h3[f] + sb1[f], 0.f) * sw2[f];
        for (int off = 32; off > 0; off >>= 1) s += __shfl_down(s, off, 64);
        if (lane == 0) {
            float content = s + sb2[0];
            int si = m & (S_ - 1);
            float imp = 1.0f / (1.0f + expf(-(content + 0.1f * pos[si])));
            if (si == 0 || si == S_ - 1) imp *= 2.0f;
            int rt = (imp > 0.8f) ? 0 : ((imp < 0.3f) ? 1 : 2);
            route[m] = rt;
            if (rt == 0) {
                int idx = atomicAdd(&flags[0], 1);
                clist[idx] = m;
            }
        }
        return;
    }
    // ---- decide_final body (block 512; barriers executed by all 256) ----
    __shared__ float qk_s[64], ce_s[128], sims_s[NC_], sc_s[8];
    __shared__ float qn_s;
    if (tid < 64) {
        qk_s[tid]      = dots[tid];
        ce_s[tid]      = fmaxf(dots[64 + tid] + cb1[tid & 63], 0.f);
        ce_s[tid + 64] = fmaxf(dots[128 + tid] + cb1[tid & 63], 0.f);
    }
    __syncthreads();
    if (tid == 0) {
        for (int b = 0; b < B_; ++b) {
            float nn = 0.f;
            for (int d = 0; d < KD_; ++d) { float v = qk_s[b * KD_ + d]; nn += v * v; }
            float den = fmaxf(sqrtf(nn), 1e-8f);
            for (int d = 0; d < KD_; ++d) qk_s[b * KD_ + d] /= den;
        }
        float qn = 0.f;
        for (int i = 0; i < B_ * KD_; ++i) qn += qk_s[i] * qk_s[i];
        qn_s = fmaxf(sqrtf(qn), 1e-8f);
    }
    __syncthreads();
    if (tid < NC_) {
        float dot = 0.f, nn = 0.f;
        for (int i = 0; i < B_ * KD_; ++i) {
            float c = ck[tid * (B_ * KD_) + i];
            dot += c * qk_s[i]; nn += c * c;
        }
        sims_s[tid] = dot / (fmaxf(sqrtf(nn), 1e-8f) * qn_s);
    }
    if (tid >= 32 && tid < 40) {
        int p = tid - 32, b = p >> 2, o = p & 3;
        float v = cb2[o];
        for (int j = 0; j < 64; ++j) v += ce_s[b * 64 + j] * cw2[o * 64 + j];
        sc_s[p] = v;
    }
    __syncthreads();
    if (tid == 0) {
        float bestv = -1e30f; int best = 0;
        for (int n = 0; n < NC_; ++n)
            if (sims_s[n] > bestv) { bestv = sims_s[n]; best = n; }
        flags[2] = (bestv >= 0.95f) ? 1 : 0;
        flags[3] = best;
        float bs = -1e30f; int bi = 0;
        for (int p = 0; p < 8; ++p)
            if (sc_s[p] > bs) { bs = sc_s[p]; bi = p; }
        flags[1] = bi & 3;
    }
}

// ---------------------------------------------------------------------------
// critstage2: merged crit_gemm (blocks 0..255) + stage2 (blocks 256..2303).
// Shared-memory union: 32KB crit dbuf tiles / ~8.7KB stage2 Ts arrays.
// ---------------------------------------------------------------------------
__global__ __launch_bounds__(256) void critstage2_kernel(
    const ushort* __restrict__ xhi, const ushort* __restrict__ lwh,
    const float* __restrict__ lb,
    const float* __restrict__ x, const float* __restrict__ Pp,
    const float* __restrict__ v4, const float* __restrict__ v12,
    const float* __restrict__ v40, const float* __restrict__ v128,
    const float* __restrict__ cd, const int* __restrict__ flags,
    const int* __restrict__ route, const int* __restrict__ clist,
    float* __restrict__ out) {
    __shared__ __align__(16) char smem[32768];
    int bi = blockIdx.x;
    int tid = threadIdx.x;

    if (bi < 256) {
        // ================= crit path: gathered-row GEMM =================
        ushort* As = (ushort*)smem;         // [2][128][32]
        ushort* Bs = As + 8192;             // [2][128][32]
        int M = flags[0];
        int m0 = (bi >> 4) << 7;
        if (m0 >= M) return;
        int n0 = (bi & 15) << 7;
        int lr = tid >> 2, lc = (tid & 3) << 3;
        int lcs = lc ^ (((lr >> 1) & 3) << 3);

        int gm0 = m0 + lr, gm1 = m0 + lr + 64;
        int ar0 = clist[gm0 < M ? gm0 : (M - 1)];
        int ar1 = clist[gm1 < M ? gm1 : (M - 1)];
        const ushort* a0p = xhi + (size_t)ar0 * H_ + lcs;
        const ushort* a1p = xhi + (size_t)ar1 * H_ + lcs;
        const ushort* b0p = lwh + (size_t)(n0 + lr) * H_ + lcs;
        const ushort* b1p = b0p + (size_t)64 * H_;

        int lane = tid & 63, w = tid >> 6;
        int wm = (w >> 1) << 6, wn = (w & 1) << 6;
        int fr = lane & 15;
        int kb = ((lane >> 4) << 3) ^ (((fr >> 1) & 3) << 3);

        f32x4 zero4 = {0.f, 0.f, 0.f, 0.f};
        f32x4 acc[4][4];
#pragma unroll
        for (int i = 0; i < 4; ++i)
#pragma unroll
            for (int j = 0; j < 4; ++j) acc[i][j] = zero4;

#define STAGE_CG(bb, k0)                                                  \
        do {                                                              \
            gld16(a0p + (k0), &As[(bb) * 4096 + lr * 32 + lc]);           \
            gld16(a1p + (k0), &As[(bb) * 4096 + (lr + 64) * 32 + lc]);    \
            gld16(b0p + (k0), &Bs[(bb) * 4096 + lr * 32 + lc]);           \
            gld16(b1p + (k0), &Bs[(bb) * 4096 + (lr + 64) * 32 + lc]);    \
        } while (0)

        STAGE_CG(0, 0);
        __syncthreads();
        int cur = 0;
        for (int kt = 0; kt < 64; ++kt) {
            if (kt + 1 < 64) STAGE_CG(cur ^ 1, (kt + 1) << 5);
            bf16x8 af[4], bf4[4];
#pragma unroll
            for (int mt = 0; mt < 4; ++mt)
                af[mt] = *(const bf16x8*)&As[cur * 4096 + (wm + (mt << 4) + fr) * 32 + kb];
#pragma unroll
            for (int nt = 0; nt < 4; ++nt)
                bf4[nt] = *(const bf16x8*)&Bs[cur * 4096 + (wn + (nt << 4) + fr) * 32 + kb];
#pragma unroll
            for (int mt = 0; mt < 4; ++mt)
#pragma unroll
                for (int nt = 0; nt < 4; ++nt)
                    acc[mt][nt] = __builtin_amdgcn_mfma_f32_16x16x32_bf16(
                        af[mt], bf4[nt], acc[mt][nt], 0, 0, 0);
            __syncthreads();
            cur ^= 1;
        }
#undef STAGE_CG

        int orr = (lane >> 4) << 2;
#pragma unroll
        for (int mt = 0; mt < 4; ++mt)
#pragma unroll
            for (int r = 0; r < 4; ++r) {
                int m = m0 + wm + (mt << 4) + orr + r;
                if (m < M) {
                    float* cr = out + (size_t)clist[m] * H_;
#pragma unroll
                    for (int nt = 0; nt < 4; ++nt) {
                        int c = n0 + wn + (nt << 4) + fr;
                        cr[c] = acc[mt][nt][r] + lb[c];
                    }
                }
            }
        return;
    }

    // ================= stage2 path =================
    float* TsR = (float*)smem;                    // [16][132]
    float* Ts4 = TsR + 16 * 132;                  // [16][4]
    int*   rt_s = (int*)(Ts4 + 64);               // [16]
    int sb = bi - 256;
    int m0 = (sb >> 4) << 4;           // token chunk
    int c0 = (sb & 15) << 7;           // column chunk (128 cols)

    if (tid < 16) rt_s[tid] = route[m0 + tid];
    int r = flags[1];
    const float* V = (r == 0) ? v4 : (r == 1) ? v12 : (r == 2) ? v40 : v128;
    int Kr  = (r == 0) ? 4 : (r == 1) ? 12 : (r == 2) ? 40 : 128;
    int off = (r == 0) ? 0 : (r == 1) ? 4  : (r == 2) ? 16 : 56;
    int hit = flags[2], best = flags[3];

    const float* Pp1 = Pp + (size_t)M_ * LDP;
    const float* Pp2 = Pp1 + (size_t)M_ * LDP;
    const float* Pp3 = Pp2 + (size_t)M_ * LDP;
    for (int idx = tid; idx < 16 * Kr; idx += 256) {
        int i = idx / Kr, j = idx - i * Kr;
        size_t o = (size_t)(m0 + i) * LDP + off + j;
        TsR[i * 132 + j] = Pp[o] + Pp1[o] + Pp2[o] + Pp3[o];
    }
    if (tid < 64) {
        int i = tid >> 2, j = tid & 3;
        size_t o = (size_t)(m0 + i) * LDP + j;
        Ts4[i * 4 + j] = Pp[o] + Pp1[o] + Pp2[o] + Pp3[o];
    }
    __syncthreads();
    bool any1 = false, any2 = false;
#pragma unroll
    for (int i = 0; i < 16; ++i) { any1 |= (rt_s[i] == 1); any2 |= (rt_s[i] == 2); }
    if (!any1 && !any2) return;
    bool need4 = any1 && !hit;

    int c = c0 + (tid & 127);
    int i0 = (tid >> 7) << 3;          // 0 or 8: token half per wave-pair

    float aR[8];
#pragma unroll
    for (int i = 0; i < 8; ++i) aR[i] = 0.f;
    if (any2) {
        const float* vrow = V + (size_t)c * Kr;
        for (int j = 0; j < Kr; j += 4) {
            const float4 vv = *(const float4*)(vrow + j);
#pragma unroll
            for (int i = 0; i < 8; ++i) {
                const float4 tv = *(const float4*)&TsR[(i0 + i) * 132 + j];
                aR[i] += tv.x * vv.x + tv.y * vv.y + tv.z * vv.z + tv.w * vv.w;
            }
        }
    }
    float a4[8];
    if (need4) {
        const float4 vv = *(const float4*)(v4 + (size_t)c * 4);
#pragma unroll
        for (int i = 0; i < 8; ++i) {
            const float4 tv = *(const float4*)&Ts4[(i0 + i) * 4];
            a4[i] = tv.x * vv.x + tv.y * vv.y + tv.z * vv.z + tv.w * vv.w;
        }
    }
#pragma unroll
    for (int i = 0; i < 8; ++i) {
        int rt = rt_s[i0 + i];
        if (rt == 0) continue;
        size_t o = (size_t)(m0 + i0 + i) * H_ + c;
        float upd;
        if (rt == 1)
            upd = hit ? cd[(size_t)best * (size_t)(M_ * H_) + o] : a4[i];
        else
            upd = aR[i];
        out[o] = x[o] + upd;
    }
}

// ---------------------------------------------------------------------------
extern "C" void kernel_launch(void* const* d_in, const int* in_sizes, int n_in,
                              void* d_out, int out_size, void* d_ws, size_t ws_size,
                              hipStream_t stream) {
    const float* x    = (const float*)d_in[0];
    const float* sw1  = (const float*)d_in[1];
    const float* sb1  = (const float*)d_in[2];
    const float* sw2  = (const float*)d_in[3];
    const float* sb2  = (const float*)d_in[4];
    const float* pos  = (const float*)d_in[5];
    const float* kpw  = (const float*)d_in[6];
    const float* ck   = (const float*)d_in[7];
    const float* cd   = (const float*)d_in[8];
    const float* cw1  = (const float*)d_in[9];
    const float* cb1  = (const float*)d_in[10];
    const float* cw2  = (const float*)d_in[11];
    const float* cb2  = (const float*)d_in[12];
    const float* u4   = (const float*)d_in[13];
    const float* v4   = (const float*)d_in[14];
    const float* u12  = (const float*)d_in[15];
    const float* v12  = (const float*)d_in[16];
    const float* u40  = (const float*)d_in[17];
    const float* v40  = (const float*)d_in[18];
    const float* u128 = (const float*)d_in[19];
    const float* v128 = (const float*)d_in[20];
    const float* lw   = (const float*)d_in[21];
    const float* lb   = (const float*)d_in[22];
    float* out = (float*)d_out;

    // ---- workspace layout (~54 MB of the 1 GiB ws) ----
    ushort* xhi = (ushort*)d_ws;                       // [M,H]
    ushort* xlo = xhi + (size_t)M_ * H_;               // [M,H]
    ushort* lwh = xlo + (size_t)M_ * H_;               // [H,H]
    ushort* swh = lwh + (size_t)H_ * H_;               // [F,H]
    ushort* swl = swh + (size_t)F_ * H_;               // [F,H]
    ushort* ubh = swl + (size_t)F_ * H_;               // [256,H] (184 valid)
    float* fbase   = (float*)(ubh + (size_t)256 * H_);
    float* partial = fbase;                            // [128,H]
    float* Pp      = partial + 128 * H_;               // [KZ_,M,LDP]
    float* Hp      = Pp + (size_t)KZ_ * M_ * LDP;      // [KZ_,M,F]
    float* dots    = Hp + (size_t)KZ_ * M_ * F_;       // [192]
    int*   flags   = (int*)(dots + 256);
    int*   route   = flags + 8;                        // [M]
    int*   clist   = route + M_;                       // [M]

    hipMemsetAsync(flags, 0, sizeof(int), stream);   // n_crit = 0

    conv_kernel<<<1500, 256, 0, stream>>>(x, lw, sw1, u4, u12, u40, u128,
                                          xhi, xlo, lwh, swh, swl, ubh, partial);
    pooldots_kernel<<<192, 256, 0, stream>>>(partial, kpw, cw1, dots);
    big_gemm<<<dim3(16, 6, KZ_), 256, 0, stream>>>(xhi, xlo, swh, swl, ubh, Hp, Pp);
    routefinal_kernel<<<513, 256, 0, stream>>>(Hp, sb1, sw2, sb2, pos,
                                               dots, ck, cb1, cw2, cb2,
                                               flags, route, clist);
    critstage2_kernel<<<2304, 256, 0, stream>>>(xhi, lwh, lb, x, Pp,
                                                v4, v12, v40, v128,
                                                cd, flags, route, clist, out);
}